// Round 1
// baseline (824.462 us; speedup 1.0000x reference)
//
#include <hip/hip_runtime.h>
#include <hip/hip_bf16.h>
#include <math.h>

// Problem constants: n=1, t=3(=L), c=64, h=w=64, M=8 heads, D=8, P=12, KK=9
#define HWN 4096

__device__ __forceinline__ float lrelu_f(float v) { return v >= 0.f ? v : 0.1f * v; }

// bilinear sample with zeros padding; valid taps are integer coords in [0,63]
__device__ __forceinline__ float bilin_zero(const float* __restrict__ img, float ix, float iy) {
  float fx0 = floorf(ix), fy0 = floorf(iy);
  int x0 = (int)fx0, y0 = (int)fy0;
  float wx1 = ix - fx0, wy1 = iy - fy0;
  float wx0 = 1.f - wx1, wy0 = 1.f - wy1;
  float acc = 0.f;
  if ((unsigned)y0 < 64u) {
    if ((unsigned)x0 < 64u)       acc += wx0 * wy0 * img[y0 * 64 + x0];
    if ((unsigned)(x0 + 1) < 64u) acc += wx1 * wy0 * img[y0 * 64 + x0 + 1];
  }
  if ((unsigned)(y0 + 1) < 64u) {
    if ((unsigned)x0 < 64u)       acc += wx0 * wy1 * img[(y0 + 1) * 64 + x0];
    if ((unsigned)(x0 + 1) < 64u) acc += wx1 * wy1 * img[(y0 + 1) * 64 + x0 + 1];
  }
  return acc;
}

// flow_cn2 = flow_1 + flow_warp(flow_2, flow_1)   (align_corners=True => ix = x + fx)
__global__ void k_flowcn2(const float* __restrict__ flow1, const float* __restrict__ flow2,
                          float* __restrict__ fcn2) {
  int p = blockIdx.x * 256 + threadIdx.x;
  int x = p & 63, y = p >> 6;
  float fx = flow1[p], fy = flow1[HWN + p];
  float ix = (float)x + fx, iy = (float)y + fy;
  float sx = bilin_zero(flow2, ix, iy);
  float sy = bilin_zero(flow2 + HWN, ix, iy);
  fcn2[p] = fx + sx;
  fcn2[HWN + p] = fy + sy;
}

// extra = concat([x0, warp(x1,flow1), warp(x2,fcn2), flow1, fcn2])  -> [196][4096]
__global__ void k_extra(const float* __restrict__ x, const float* __restrict__ flow1,
                        const float* __restrict__ fcn2, float* __restrict__ extra) {
  int p = blockIdx.x * 256 + threadIdx.x;
  int c = blockIdx.y;  // 0..63
  int xx = p & 63, yy = p >> 6;
  extra[c * HWN + p] = x[c * HWN + p];
  float ix1 = (float)xx + flow1[p],   iy1 = (float)yy + flow1[HWN + p];
  float ix2 = (float)xx + fcn2[p],    iy2 = (float)yy + fcn2[HWN + p];
  extra[(64 + c) * HWN + p]  = bilin_zero(x + (64 + c) * HWN,  ix1, iy1);
  extra[(128 + c) * HWN + p] = bilin_zero(x + (128 + c) * HWN, ix2, iy2);
  if (c < 2) {
    extra[(192 + c) * HWN + p] = flow1[c * HWN + p];
    extra[(194 + c) * HWN + p] = fcn2[c * HWN + p];
  }
}

// Generic direct 1x1 conv: out[co][p] = b[co] + sum_ci w[co][ci] * in[ci][p]
// ACT: 0 none, 1 lrelu.  MODE: 0 plain [co][p]; 1 value layout [(co/8)][p][co%8]; 2 plain + add[co][p]
template <int CIN, int G, int ACT, int MODE>
__global__ void k_conv1x1(const float* __restrict__ in, const float* __restrict__ w,
                          const float* __restrict__ b, float* __restrict__ out,
                          const float* __restrict__ add) {
  int p = blockIdx.x * 256 + threadIdx.x;
  int cog = blockIdx.y;
  float acc[G];
#pragma unroll
  for (int g = 0; g < G; g++) acc[g] = b[cog * G + g];
  const float* wp = w + (size_t)cog * G * CIN;
  for (int ci = 0; ci < CIN; ci++) {
    float v = in[ci * HWN + p];
#pragma unroll
    for (int g = 0; g < G; g++) acc[g] += wp[g * CIN + ci] * v;
  }
#pragma unroll
  for (int g = 0; g < G; g++) {
    int co = cog * G + g;
    float r = acc[g];
    if (ACT == 1) r = lrelu_f(r);
    if (MODE == 0) {
      out[(size_t)co * HWN + p] = r;
    } else if (MODE == 1) {
      out[(size_t)((co >> 3) * HWN + p) * 8 + (co & 7)] = r;
    } else {
      out[(size_t)co * HWN + p] = r + add[(size_t)co * HWN + p];
    }
  }
}

// Direct 3x3 conv 64->64, pad 1, lrelu. thread = (pixel, G out-channels)
template <int G>
__global__ void k_conv3x3(const float* __restrict__ in, const float* __restrict__ w,
                          const float* __restrict__ b, float* __restrict__ out) {
  int p = blockIdx.x * 256 + threadIdx.x;
  int cog = blockIdx.y;
  int x = p & 63, y = p >> 6;
  float acc[G];
#pragma unroll
  for (int g = 0; g < G; g++) acc[g] = b[cog * G + g];
  const float* wp = w + (size_t)cog * G * 64 * 9;
  for (int ci = 0; ci < 64; ci++) {
    const float* ip = in + ci * HWN;
#pragma unroll
    for (int ky = 0; ky < 3; ky++) {
      int yy = y + ky - 1;
      bool vy = ((unsigned)yy < 64u);
#pragma unroll
      for (int kx = 0; kx < 3; kx++) {
        int xx = x + kx - 1;
        float v = (vy && (unsigned)xx < 64u) ? ip[yy * 64 + xx] : 0.f;
#pragma unroll
        for (int g = 0; g < G; g++) acc[g] += wp[(g * 64 + ci) * 9 + ky * 3 + kx] * v;
      }
    }
  }
#pragma unroll
  for (int g = 0; g < G; g++) out[(size_t)(cog * G + g) * HWN + p] = lrelu_f(acc[g]);
}

// Fused: per (pixel, head): softmax over 324 logits, sample value (8 ch, bilinear,
// zeros pad, align_corners=False which reduces to ix = x + total_offset), weighted sum.
// vs layout: [(l*8+m)][pixel][d], d contiguous (8 floats)
__global__ void k_msdeform(const float* __restrict__ vs, const float* __restrict__ offo,
                           const float* __restrict__ poo, const float* __restrict__ awo,
                           const float* __restrict__ flow1, const float* __restrict__ fcn2,
                           float* __restrict__ feat) {
  int tid = blockIdx.x * 256 + threadIdx.x;  // 32768
  int p = tid & (HWN - 1);
  int m = tid >> 12;  // 0..7
  int x = p & 63, y = p >> 6;

  const float* awp = awo + (size_t)m * 324 * HWN + p;
  float mx = -1e30f;
  for (int j = 0; j < 324; j++) mx = fmaxf(mx, awp[(size_t)j * HWN]);

  float acc[8];
#pragma unroll
  for (int d = 0; d < 8; d++) acc[d] = 0.f;
  float wsum = 0.f;

  for (int l = 0; l < 3; l++) {
    float fx = 0.f, fy = 0.f;
    if (l == 1) { fx = flow1[p]; fy = flow1[HWN + p]; }
    if (l == 2) { fx = fcn2[p];  fy = fcn2[HWN + p]; }
    const float* vbase = vs + (size_t)(l * 8 + m) * HWN * 8;
    for (int pt = 0; pt < 12; pt++) {
      int ch = (m * 3 + l) * 12 + pt;
      float ox = offo[(size_t)(ch * 2 + 0) * HWN + p];
      float oy = offo[(size_t)(ch * 2 + 1) * HWN + p];
      float s = 3.f / (1.f + __expf(-poo[(size_t)ch * HWN + p]));
      float bx = (float)x + ox + fx;
      float by = (float)y + oy + fy;
#pragma unroll
      for (int kk = 0; kk < 9; kk++) {
        float pnx = (float)(kk / 3 - 1);
        float pny = (float)(kk % 3 - 1);
        float ix = bx + pnx * s;
        float iy = by + pny * s;
        float lg = awp[(size_t)(l * 108 + pt * 9 + kk) * HWN];
        float wgt = __expf(lg - mx);
        wsum += wgt;

        float fx0 = floorf(ix), fy0 = floorf(iy);
        int x0 = (int)fx0, y0 = (int)fy0;
        float wx1 = ix - fx0, wy1 = iy - fy0;
        float wx0 = 1.f - wx1, wy0 = 1.f - wy1;

        float tw[4];
        int tx[4], ty[4];
        tw[0] = wx0 * wy0; tx[0] = x0;     ty[0] = y0;
        tw[1] = wx1 * wy0; tx[1] = x0 + 1; ty[1] = y0;
        tw[2] = wx0 * wy1; tx[2] = x0;     ty[2] = y0 + 1;
        tw[3] = wx1 * wy1; tx[3] = x0 + 1; ty[3] = y0 + 1;
#pragma unroll
        for (int t = 0; t < 4; t++) {
          if ((unsigned)tx[t] < 64u && (unsigned)ty[t] < 64u) {
            const float4* vp4 = (const float4*)(vbase + (size_t)(ty[t] * 64 + tx[t]) * 8);
            float4 a0 = vp4[0], a1 = vp4[1];
            float ww = wgt * tw[t];
            acc[0] += ww * a0.x; acc[1] += ww * a0.y; acc[2] += ww * a0.z; acc[3] += ww * a0.w;
            acc[4] += ww * a1.x; acc[5] += ww * a1.y; acc[6] += ww * a1.z; acc[7] += ww * a1.w;
          }
        }
      }
    }
  }
  float inv = 1.f / wsum;
#pragma unroll
  for (int d = 0; d < 8; d++) feat[(size_t)(m * 8 + d) * HWN + p] = acc[d] * inv;
}

extern "C" void kernel_launch(void* const* d_in, const int* in_sizes, int n_in,
                              void* d_out, int out_size, void* d_ws, size_t ws_size,
                              hipStream_t stream) {
  const float* x     = (const float*)d_in[0];
  const float* flow1 = (const float*)d_in[1];
  const float* flow2 = (const float*)d_in[2];
  // d_in[3], d_in[4] (flip flows) unused by forward
  const float* aw_w1 = (const float*)d_in[5];
  const float* aw_b1 = (const float*)d_in[6];
  const float* aw_w2 = (const float*)d_in[7];
  const float* aw_b2 = (const float*)d_in[8];
  const float* aw_w3 = (const float*)d_in[9];
  const float* aw_b3 = (const float*)d_in[10];
  const float* aw_w4 = (const float*)d_in[11];
  const float* aw_b4 = (const float*)d_in[12];
  const float* so_w1 = (const float*)d_in[13];
  const float* so_b1 = (const float*)d_in[14];
  const float* so_w2 = (const float*)d_in[15];
  const float* so_b2 = (const float*)d_in[16];
  const float* so_w3 = (const float*)d_in[17];
  const float* so_b3 = (const float*)d_in[18];
  const float* so_w4 = (const float*)d_in[19];
  const float* so_b4 = (const float*)d_in[20];
  const float* po_w1 = (const float*)d_in[21];
  const float* po_b1 = (const float*)d_in[22];
  const float* po_w2 = (const float*)d_in[23];
  const float* po_b2 = (const float*)d_in[24];
  const float* po_w3 = (const float*)d_in[25];
  const float* po_b3 = (const float*)d_in[26];
  const float* po_w4 = (const float*)d_in[27];
  const float* po_b4 = (const float*)d_in[28];
  const float* vp_w  = (const float*)d_in[29];
  const float* vp_b  = (const float*)d_in[30];
  const float* op_w1 = (const float*)d_in[31];
  const float* op_b1 = (const float*)d_in[32];
  const float* op_w2 = (const float*)d_in[33];
  const float* op_b2 = (const float*)d_in[34];

  float* ws    = (float*)d_ws;
  float* fcn2  = ws;                      // 2*4096
  float* extra = fcn2 + 2 * HWN;          // 196*4096
  float* vs    = extra + 196 * HWN;       // 24*4096*8 = 192*4096
  float* bufA  = vs + 192 * HWN;          // 64*4096
  float* bufB  = bufA + 64 * HWN;         // 64*4096
  float* off_o = bufB + 64 * HWN;         // 576*4096
  float* po_o  = off_o + 576 * HWN;       // 288*4096
  float* aw_o  = po_o + 288 * HWN;        // 2592*4096
  float* feat  = aw_o + 2592 * HWN;       // 64*4096
  float* hop   = feat + 64 * HWN;         // 64*4096

  k_flowcn2<<<16, 256, 0, stream>>>(flow1, flow2, fcn2);
  k_extra<<<dim3(16, 64), 256, 0, stream>>>(x, flow1, fcn2, extra);

  // value projection 192->192 (1x1), written in sampling layout
  k_conv1x1<192, 8, 0, 1><<<dim3(16, 24), 256, 0, stream>>>(x, vp_w, vp_b, vs, nullptr);

  // so trunk -> offsets (576 ch)
  k_conv1x1<196, 4, 1, 0><<<dim3(16, 16), 256, 0, stream>>>(extra, so_w1, so_b1, bufA, nullptr);
  k_conv3x3<4><<<dim3(16, 16), 256, 0, stream>>>(bufA, so_w2, so_b2, bufB);
  k_conv3x3<4><<<dim3(16, 16), 256, 0, stream>>>(bufB, so_w3, so_b3, bufA);
  k_conv1x1<64, 16, 0, 0><<<dim3(16, 36), 256, 0, stream>>>(bufA, so_w4, so_b4, off_o, nullptr);

  // po trunk -> patch scales (288 ch)
  k_conv1x1<196, 4, 1, 0><<<dim3(16, 16), 256, 0, stream>>>(extra, po_w1, po_b1, bufA, nullptr);
  k_conv3x3<4><<<dim3(16, 16), 256, 0, stream>>>(bufA, po_w2, po_b2, bufB);
  k_conv3x3<4><<<dim3(16, 16), 256, 0, stream>>>(bufB, po_w3, po_b3, bufA);
  k_conv1x1<64, 16, 0, 0><<<dim3(16, 18), 256, 0, stream>>>(bufA, po_w4, po_b4, po_o, nullptr);

  // aw trunk -> attention logits (2592 ch)
  k_conv1x1<196, 4, 1, 0><<<dim3(16, 16), 256, 0, stream>>>(extra, aw_w1, aw_b1, bufA, nullptr);
  k_conv3x3<4><<<dim3(16, 16), 256, 0, stream>>>(bufA, aw_w2, aw_b2, bufB);
  k_conv3x3<4><<<dim3(16, 16), 256, 0, stream>>>(bufB, aw_w3, aw_b3, bufA);
  k_conv1x1<64, 16, 0, 0><<<dim3(16, 162), 256, 0, stream>>>(bufA, aw_w4, aw_b4, aw_o, nullptr);

  // fused softmax + deformable sampling -> feat [64][4096]
  k_msdeform<<<128, 256, 0, stream>>>(vs, off_o, po_o, aw_o, flow1, fcn2, feat);

  // output convs: res = op2(lrelu(op1(feat))); out = res + x[:,0]
  k_conv1x1<64, 4, 1, 0><<<dim3(16, 16), 256, 0, stream>>>(feat, op_w1, op_b1, hop, nullptr);
  k_conv1x1<64, 4, 0, 2><<<dim3(16, 16), 256, 0, stream>>>(hop, op_w2, op_b2, (float*)d_out, x);
}

// Round 2
// 539.781 us; speedup vs baseline: 1.5274x; 1.5274x over previous
//
#include <hip/hip_runtime.h>
#include <hip/hip_bf16.h>
#include <math.h>

// Problem constants: n=1, t=3(=L), c=64, h=w=64, M=8 heads, D=8, P=12, KK=9
#define HWN 4096

__device__ __forceinline__ float lrelu_f(float v) { return v >= 0.f ? v : 0.1f * v; }

// bilinear sample with zeros padding; valid taps are integer coords in [0,63]
__device__ __forceinline__ float bilin_zero(const float* __restrict__ img, float ix, float iy) {
  float fx0 = floorf(ix), fy0 = floorf(iy);
  int x0 = (int)fx0, y0 = (int)fy0;
  float wx1 = ix - fx0, wy1 = iy - fy0;
  float wx0 = 1.f - wx1, wy0 = 1.f - wy1;
  float acc = 0.f;
  if ((unsigned)y0 < 64u) {
    if ((unsigned)x0 < 64u)       acc += wx0 * wy0 * img[y0 * 64 + x0];
    if ((unsigned)(x0 + 1) < 64u) acc += wx1 * wy0 * img[y0 * 64 + x0 + 1];
  }
  if ((unsigned)(y0 + 1) < 64u) {
    if ((unsigned)x0 < 64u)       acc += wx0 * wy1 * img[(y0 + 1) * 64 + x0];
    if ((unsigned)(x0 + 1) < 64u) acc += wx1 * wy1 * img[(y0 + 1) * 64 + x0 + 1];
  }
  return acc;
}

// flow_cn2 = flow_1 + flow_warp(flow_2, flow_1)   (align_corners=True => ix = x + fx)
__global__ void k_flowcn2(const float* __restrict__ flow1, const float* __restrict__ flow2,
                          float* __restrict__ fcn2) {
  int p = blockIdx.x * 256 + threadIdx.x;
  int x = p & 63, y = p >> 6;
  float fx = flow1[p], fy = flow1[HWN + p];
  float ix = (float)x + fx, iy = (float)y + fy;
  float sx = bilin_zero(flow2, ix, iy);
  float sy = bilin_zero(flow2 + HWN, ix, iy);
  fcn2[p] = fx + sx;
  fcn2[HWN + p] = fy + sy;
}

// extra = concat([x0, warp(x1,flow1), warp(x2,fcn2), flow1, fcn2])  -> [196][4096]
__global__ void k_extra(const float* __restrict__ x, const float* __restrict__ flow1,
                        const float* __restrict__ fcn2, float* __restrict__ extra) {
  int p = blockIdx.x * 256 + threadIdx.x;
  int c = blockIdx.y;  // 0..63
  int xx = p & 63, yy = p >> 6;
  extra[c * HWN + p] = x[c * HWN + p];
  float ix1 = (float)xx + flow1[p],   iy1 = (float)yy + flow1[HWN + p];
  float ix2 = (float)xx + fcn2[p],    iy2 = (float)yy + fcn2[HWN + p];
  extra[(64 + c) * HWN + p]  = bilin_zero(x + (64 + c) * HWN,  ix1, iy1);
  extra[(128 + c) * HWN + p] = bilin_zero(x + (128 + c) * HWN, ix2, iy2);
  if (c < 2) {
    extra[(192 + c) * HWN + p] = flow1[c * HWN + p];
    extra[(194 + c) * HWN + p] = fcn2[c * HWN + p];
  }
}

// Generic direct 1x1 conv: out[co][p] = b[co] + sum_ci w[co][ci] * in[ci][p]
// ACT: 0 none, 1 lrelu.  MODE: 0 plain [co][p]; 1 value layout [(co/8)][p][co%8]; 2 plain + add[co][p]
template <int CIN, int G, int ACT, int MODE>
__global__ void k_conv1x1(const float* __restrict__ in, const float* __restrict__ w,
                          const float* __restrict__ b, float* __restrict__ out,
                          const float* __restrict__ add) {
  int p = blockIdx.x * 256 + threadIdx.x;
  int cog = blockIdx.y;
  float acc[G];
#pragma unroll
  for (int g = 0; g < G; g++) acc[g] = b[cog * G + g];
  const float* wp = w + (size_t)cog * G * CIN;
  for (int ci = 0; ci < CIN; ci++) {
    float v = in[ci * HWN + p];
#pragma unroll
    for (int g = 0; g < G; g++) acc[g] += wp[g * CIN + ci] * v;
  }
#pragma unroll
  for (int g = 0; g < G; g++) {
    int co = cog * G + g;
    float r = acc[g];
    if (ACT == 1) r = lrelu_f(r);
    if (MODE == 0) {
      out[(size_t)co * HWN + p] = r;
    } else if (MODE == 1) {
      out[(size_t)((co >> 3) * HWN + p) * 8 + (co & 7)] = r;
    } else {
      out[(size_t)co * HWN + p] = r + add[(size_t)co * HWN + p];
    }
  }
}

// Direct 3x3 conv 64->64, pad 1, lrelu. thread = (pixel, G out-channels)
template <int G>
__global__ void k_conv3x3(const float* __restrict__ in, const float* __restrict__ w,
                          const float* __restrict__ b, float* __restrict__ out) {
  int p = blockIdx.x * 256 + threadIdx.x;
  int cog = blockIdx.y;
  int x = p & 63, y = p >> 6;
  float acc[G];
#pragma unroll
  for (int g = 0; g < G; g++) acc[g] = b[cog * G + g];
  const float* wp = w + (size_t)cog * G * 64 * 9;
  for (int ci = 0; ci < 64; ci++) {
    const float* ip = in + ci * HWN;
#pragma unroll
    for (int ky = 0; ky < 3; ky++) {
      int yy = y + ky - 1;
      bool vy = ((unsigned)yy < 64u);
#pragma unroll
      for (int kx = 0; kx < 3; kx++) {
        int xx = x + kx - 1;
        float v = (vy && (unsigned)xx < 64u) ? ip[yy * 64 + xx] : 0.f;
#pragma unroll
        for (int g = 0; g < G; g++) acc[g] += wp[(g * 64 + ci) * 9 + ky * 3 + kx] * v;
      }
    }
  }
#pragma unroll
  for (int g = 0; g < G; g++) out[(size_t)(cog * G + g) * HWN + p] = lrelu_f(acc[g]);
}

// Fused softmax + deformable sampling.
// Work split: 8 lanes (low 3 bits of tid) cooperate on one (pixel, head).
// Each lane handles (l,pt) pairs y, y+8, ..., then shfl_xor-reduce acc/wsum.
// Softmax computed WITHOUT max subtraction (logits are 0.01-scaled conv outputs,
// |logit| << 80, and softmax is shift-invariant).
// vs layout: [(l*8+m)][pixel][d], d contiguous (8 floats)
__global__ void k_msdeform(const float* __restrict__ vs, const float* __restrict__ offo,
                           const float* __restrict__ poo, const float* __restrict__ awo,
                           const float* __restrict__ flow1, const float* __restrict__ fcn2,
                           float* __restrict__ feat) {
  int yl = threadIdx.x & 7;                     // split index 0..7
  int p = blockIdx.x * 32 + (threadIdx.x >> 3); // pixel
  int m = blockIdx.y;                           // head
  int px = p & 63, py = p >> 6;

  float fx1 = flow1[p], fy1 = flow1[HWN + p];
  float fx2 = fcn2[p],  fy2 = fcn2[HWN + p];

  const float* awp = awo + (size_t)m * 324 * HWN + p;

  float acc[8];
#pragma unroll
  for (int d = 0; d < 8; d++) acc[d] = 0.f;
  float wsum = 0.f;

  for (int pair = yl; pair < 36; pair += 8) {
    int l = pair / 12, pt = pair % 12;
    float fx = (l == 1) ? fx1 : ((l == 2) ? fx2 : 0.f);
    float fy = (l == 1) ? fy1 : ((l == 2) ? fy2 : 0.f);
    int ch = (m * 3 + l) * 12 + pt;
    float ox = offo[(size_t)(ch * 2 + 0) * HWN + p];
    float oy = offo[(size_t)(ch * 2 + 1) * HWN + p];
    float s = 3.f / (1.f + __expf(-poo[(size_t)ch * HWN + p]));
    float bx = (float)px + ox + fx;
    float by = (float)py + oy + fy;
    const float* vbase = vs + (size_t)(l * 8 + m) * HWN * 8;
    const float* lgp = awp + (size_t)(l * 108 + pt * 9) * HWN;
#pragma unroll
    for (int kk = 0; kk < 9; kk++) {
      float pnx = (float)(kk / 3 - 1);
      float pny = (float)(kk % 3 - 1);
      float ix = bx + pnx * s;
      float iy = by + pny * s;
      float wgt = __expf(lgp[(size_t)kk * HWN]);
      wsum += wgt;

      float fx0 = floorf(ix), fy0 = floorf(iy);
      int x0 = (int)fx0, y0 = (int)fy0;
      float wx1 = ix - fx0, wy1 = iy - fy0;
      float wx0 = 1.f - wx1, wy0 = 1.f - wy1;

      float tw[4];
      int tx[4], ty[4];
      tw[0] = wx0 * wy0; tx[0] = x0;     ty[0] = y0;
      tw[1] = wx1 * wy0; tx[1] = x0 + 1; ty[1] = y0;
      tw[2] = wx0 * wy1; tx[2] = x0;     ty[2] = y0 + 1;
      tw[3] = wx1 * wy1; tx[3] = x0 + 1; ty[3] = y0 + 1;
#pragma unroll
      for (int t = 0; t < 4; t++) {
        if ((unsigned)tx[t] < 64u && (unsigned)ty[t] < 64u) {
          const float4* vp4 = (const float4*)(vbase + (size_t)(ty[t] * 64 + tx[t]) * 8);
          float4 a0 = vp4[0], a1 = vp4[1];
          float ww = wgt * tw[t];
          acc[0] += ww * a0.x; acc[1] += ww * a0.y; acc[2] += ww * a0.z; acc[3] += ww * a0.w;
          acc[4] += ww * a1.x; acc[5] += ww * a1.y; acc[6] += ww * a1.z; acc[7] += ww * a1.w;
        }
      }
    }
  }

  // reduce across the 8 cooperating lanes (same p, yl = 0..7 in low bits)
#pragma unroll
  for (int mask = 1; mask < 8; mask <<= 1) {
    wsum += __shfl_xor(wsum, mask);
#pragma unroll
    for (int d = 0; d < 8; d++) acc[d] += __shfl_xor(acc[d], mask);
  }
  float inv = 1.f / wsum;
  // lane yl writes channel d = yl (select acc[yl] without dynamic indexing)
  float r = 0.f;
#pragma unroll
  for (int d = 0; d < 8; d++) r = (d == yl) ? acc[d] : r;
  feat[(size_t)(m * 8 + yl) * HWN + p] = r * inv;
}

extern "C" void kernel_launch(void* const* d_in, const int* in_sizes, int n_in,
                              void* d_out, int out_size, void* d_ws, size_t ws_size,
                              hipStream_t stream) {
  const float* x     = (const float*)d_in[0];
  const float* flow1 = (const float*)d_in[1];
  const float* flow2 = (const float*)d_in[2];
  // d_in[3], d_in[4] (flip flows) unused by forward
  const float* aw_w1 = (const float*)d_in[5];
  const float* aw_b1 = (const float*)d_in[6];
  const float* aw_w2 = (const float*)d_in[7];
  const float* aw_b2 = (const float*)d_in[8];
  const float* aw_w3 = (const float*)d_in[9];
  const float* aw_b3 = (const float*)d_in[10];
  const float* aw_w4 = (const float*)d_in[11];
  const float* aw_b4 = (const float*)d_in[12];
  const float* so_w1 = (const float*)d_in[13];
  const float* so_b1 = (const float*)d_in[14];
  const float* so_w2 = (const float*)d_in[15];
  const float* so_b2 = (const float*)d_in[16];
  const float* so_w3 = (const float*)d_in[17];
  const float* so_b3 = (const float*)d_in[18];
  const float* so_w4 = (const float*)d_in[19];
  const float* so_b4 = (const float*)d_in[20];
  const float* po_w1 = (const float*)d_in[21];
  const float* po_b1 = (const float*)d_in[22];
  const float* po_w2 = (const float*)d_in[23];
  const float* po_b2 = (const float*)d_in[24];
  const float* po_w3 = (const float*)d_in[25];
  const float* po_b3 = (const float*)d_in[26];
  const float* po_w4 = (const float*)d_in[27];
  const float* po_b4 = (const float*)d_in[28];
  const float* vp_w  = (const float*)d_in[29];
  const float* vp_b  = (const float*)d_in[30];
  const float* op_w1 = (const float*)d_in[31];
  const float* op_b1 = (const float*)d_in[32];
  const float* op_w2 = (const float*)d_in[33];
  const float* op_b2 = (const float*)d_in[34];

  float* ws    = (float*)d_ws;
  float* fcn2  = ws;                      // 2*4096
  float* extra = fcn2 + 2 * HWN;          // 196*4096
  float* vs    = extra + 196 * HWN;       // 24*4096*8 = 192*4096
  float* bufA  = vs + 192 * HWN;          // 64*4096
  float* bufB  = bufA + 64 * HWN;         // 64*4096
  float* off_o = bufB + 64 * HWN;         // 576*4096
  float* po_o  = off_o + 576 * HWN;       // 288*4096
  float* aw_o  = po_o + 288 * HWN;        // 2592*4096
  float* feat  = aw_o + 2592 * HWN;       // 64*4096
  float* hop   = feat + 64 * HWN;         // 64*4096

  k_flowcn2<<<16, 256, 0, stream>>>(flow1, flow2, fcn2);
  k_extra<<<dim3(16, 64), 256, 0, stream>>>(x, flow1, fcn2, extra);

  // value projection 192->192 (1x1), written in sampling layout
  k_conv1x1<192, 8, 0, 1><<<dim3(16, 24), 256, 0, stream>>>(x, vp_w, vp_b, vs, nullptr);

  // so trunk -> offsets (576 ch)
  k_conv1x1<196, 4, 1, 0><<<dim3(16, 16), 256, 0, stream>>>(extra, so_w1, so_b1, bufA, nullptr);
  k_conv3x3<4><<<dim3(16, 16), 256, 0, stream>>>(bufA, so_w2, so_b2, bufB);
  k_conv3x3<4><<<dim3(16, 16), 256, 0, stream>>>(bufB, so_w3, so_b3, bufA);
  k_conv1x1<64, 16, 0, 0><<<dim3(16, 36), 256, 0, stream>>>(bufA, so_w4, so_b4, off_o, nullptr);

  // po trunk -> patch scales (288 ch)
  k_conv1x1<196, 4, 1, 0><<<dim3(16, 16), 256, 0, stream>>>(extra, po_w1, po_b1, bufA, nullptr);
  k_conv3x3<4><<<dim3(16, 16), 256, 0, stream>>>(bufA, po_w2, po_b2, bufB);
  k_conv3x3<4><<<dim3(16, 16), 256, 0, stream>>>(bufB, po_w3, po_b3, bufA);
  k_conv1x1<64, 16, 0, 0><<<dim3(16, 18), 256, 0, stream>>>(bufA, po_w4, po_b4, po_o, nullptr);

  // aw trunk -> attention logits (2592 ch)
  k_conv1x1<196, 4, 1, 0><<<dim3(16, 16), 256, 0, stream>>>(extra, aw_w1, aw_b1, bufA, nullptr);
  k_conv3x3<4><<<dim3(16, 16), 256, 0, stream>>>(bufA, aw_w2, aw_b2, bufB);
  k_conv3x3<4><<<dim3(16, 16), 256, 0, stream>>>(bufB, aw_w3, aw_b3, bufA);
  k_conv1x1<64, 16, 0, 0><<<dim3(16, 162), 256, 0, stream>>>(bufA, aw_w4, aw_b4, aw_o, nullptr);

  // fused softmax + deformable sampling -> feat [64][4096]
  // 8 lanes cooperate per (pixel, head): 1024 blocks -> 16 waves/CU
  k_msdeform<<<dim3(128, 8), 256, 0, stream>>>(vs, off_o, po_o, aw_o, flow1, fcn2, feat);

  // output convs: res = op2(lrelu(op1(feat))); out = res + x[:,0]
  k_conv1x1<64, 4, 1, 0><<<dim3(16, 16), 256, 0, stream>>>(feat, op_w1, op_b1, hop, nullptr);
  k_conv1x1<64, 4, 0, 2><<<dim3(16, 16), 256, 0, stream>>>(hop, op_w2, op_b2, (float*)d_out, x);
}

// Round 3
// 306.638 us; speedup vs baseline: 2.6887x; 1.7603x over previous
//
#include <hip/hip_runtime.h>
#include <hip/hip_bf16.h>
#include <math.h>

// Problem constants: n=1, t=3(=L), c=64, h=w=64, M=8 heads, D=8, P=12, KK=9
#define HWN 4096

typedef __attribute__((ext_vector_type(8))) short short8;   // 8 bf16 (4 VGPRs)
typedef __attribute__((ext_vector_type(4))) float f32x4;    // MFMA C/D

__device__ __forceinline__ float lrelu_f(float v) { return v >= 0.f ? v : 0.1f * v; }

__device__ __forceinline__ unsigned short f2bf(float f) {
  union { float f; unsigned u; } v; v.f = f;
  unsigned r = v.u + 0x7fff + ((v.u >> 16) & 1);   // round-to-nearest-even
  return (unsigned short)(r >> 16);
}
__device__ __forceinline__ float bf2f(unsigned short u) {
  union { unsigned u; float f; } v; v.u = ((unsigned)u) << 16;
  return v.f;
}

// bilinear sample with zeros padding (fp32 source)
__device__ __forceinline__ float bilin_zero(const float* __restrict__ img, float ix, float iy) {
  float fx0 = floorf(ix), fy0 = floorf(iy);
  int x0 = (int)fx0, y0 = (int)fy0;
  float wx1 = ix - fx0, wy1 = iy - fy0;
  float wx0 = 1.f - wx1, wy0 = 1.f - wy1;
  float acc = 0.f;
  if ((unsigned)y0 < 64u) {
    if ((unsigned)x0 < 64u)       acc += wx0 * wy0 * img[y0 * 64 + x0];
    if ((unsigned)(x0 + 1) < 64u) acc += wx1 * wy0 * img[y0 * 64 + x0 + 1];
  }
  if ((unsigned)(y0 + 1) < 64u) {
    if ((unsigned)x0 < 64u)       acc += wx0 * wy1 * img[(y0 + 1) * 64 + x0];
    if ((unsigned)(x0 + 1) < 64u) acc += wx1 * wy1 * img[(y0 + 1) * 64 + x0 + 1];
  }
  return acc;
}

// flow_cn2 = flow_1 + flow_warp(flow_2, flow_1)
__global__ void k_flowcn2(const float* __restrict__ flow1, const float* __restrict__ flow2,
                          float* __restrict__ fcn2) {
  int p = blockIdx.x * 256 + threadIdx.x;
  int x = p & 63, y = p >> 6;
  float fx = flow1[p], fy = flow1[HWN + p];
  float ix = (float)x + fx, iy = (float)y + fy;
  fcn2[p] = fx + bilin_zero(flow2, ix, iy);
  fcn2[HWN + p] = fy + bilin_zero(flow2 + HWN, ix, iy);
}

// extra[p][224] bf16 (196 real + 28 zero-pad) and xb[p][192] bf16 (value-proj input)
__global__ void k_extra(const float* __restrict__ x, const float* __restrict__ flow1,
                        const float* __restrict__ fcn2, unsigned short* __restrict__ extra,
                        unsigned short* __restrict__ xb) {
  int p = blockIdx.x * 256 + threadIdx.x;
  int c = blockIdx.y;  // 0..63
  int xx = p & 63, yy = p >> 6;
  float x0 = x[c * HWN + p];
  float x1 = x[(64 + c) * HWN + p];
  float x2 = x[(128 + c) * HWN + p];
  xb[p * 192 + c]        = f2bf(x0);
  xb[p * 192 + 64 + c]   = f2bf(x1);
  xb[p * 192 + 128 + c]  = f2bf(x2);
  extra[p * 224 + c] = f2bf(x0);
  float ix1 = (float)xx + flow1[p], iy1 = (float)yy + flow1[HWN + p];
  float ix2 = (float)xx + fcn2[p],  iy2 = (float)yy + fcn2[HWN + p];
  extra[p * 224 + 64 + c]  = f2bf(bilin_zero(x + (64 + c) * HWN, ix1, iy1));
  extra[p * 224 + 128 + c] = f2bf(bilin_zero(x + (128 + c) * HWN, ix2, iy2));
  if (c < 2) {
    extra[p * 224 + 192 + c] = f2bf(flow1[c * HWN + p]);
    extra[p * 224 + 194 + c] = f2bf(fcn2[c * HWN + p]);
  }
  if (c < 28) extra[p * 224 + 196 + c] = 0;
}

// Weight fp32 -> bf16 staging (15 tensors, one launch, branch on blockIdx.y)
__global__ void k_wconv(
    const float* s0, const float* s1, const float* s2, const float* s3,
    const float* s4, const float* s5, const float* s6, const float* s7,
    const float* s8, const float* s9, const float* s10, const float* s11,
    const float* s12, const float* s13, const float* s14,
    unsigned short* d0, unsigned short* d1, unsigned short* d2, unsigned short* d3,
    unsigned short* d4, unsigned short* d5, unsigned short* d6, unsigned short* d7,
    unsigned short* d8, unsigned short* d9, unsigned short* d10, unsigned short* d11,
    unsigned short* d12, unsigned short* d13, unsigned short* d14) {
  int t = blockIdx.x * 256 + threadIdx.x;
  int y = blockIdx.y;
  if (y < 6) {  // plain elementwise cast: [CO][K] layout preserved
    const float* s = y == 0 ? s0 : y == 1 ? s1 : y == 2 ? s2 : y == 3 ? s3 : y == 4 ? s4 : s5;
    unsigned short* d = y == 0 ? d0 : y == 1 ? d1 : y == 2 ? d2 : y == 3 ? d3 : y == 4 ? d4 : d5;
    int n = y == 0 ? 2592 * 64 : y == 1 ? 576 * 64 : y == 2 ? 288 * 64 : y == 3 ? 192 * 192 : 64 * 64;
    if (t < n) d[t] = f2bf(s[t]);
  } else if (y < 9) {  // head convs: [64][196] -> [64][224] zero-padded
    const float* s = y == 6 ? s6 : y == 7 ? s7 : s8;
    unsigned short* d = y == 6 ? d6 : y == 7 ? d7 : d8;
    if (t < 64 * 224) {
      int co = t / 224, k = t % 224;
      d[t] = (k < 196) ? f2bf(s[co * 196 + k]) : (unsigned short)0;
    }
  } else {  // 3x3 convs: w[co][ci][kidx] -> wb[co][kidx*64+ci]
    const float* s = y == 9 ? s9 : y == 10 ? s10 : y == 11 ? s11 : y == 12 ? s12 : y == 13 ? s13 : s14;
    unsigned short* d = y == 9 ? d9 : y == 10 ? d10 : y == 11 ? d11 : y == 12 ? d12 : y == 13 ? d13 : d14;
    if (t < 64 * 576) {
      int co = t / 576, rem = t % 576;
      int kidx = rem >> 6, ci = rem & 63;
      d[t] = f2bf(s[co * 576 + ci * 9 + kidx]);
    }
  }
}

// im2col for 3x3 pad-1: in [p][64] bf16 -> X9 [p][kidx*64+ci] bf16, zeros at borders
__global__ void k_im2col(const unsigned short* __restrict__ in, unsigned short* __restrict__ X9) {
  int g = blockIdx.x * 256 + threadIdx.x;  // 4096 * 72
  int p = g / 72, c = g % 72;
  int kidx = c >> 3, ci0 = (c & 7) * 8;
  int ky = kidx / 3, kx = kidx % 3;
  int xx = p & 63, yy = p >> 6;
  int xs = xx + kx - 1, ys = yy + ky - 1;
  uint4 val = make_uint4(0, 0, 0, 0);
  if ((unsigned)xs < 64u && (unsigned)ys < 64u)
    val = *(const uint4*)(in + (size_t)(ys * 64 + xs) * 64 + ci0);
  *(uint4*)(X9 + (size_t)p * 576 + kidx * 64 + ci0) = val;
}

// MFMA GEMM: C[p][co] = bias[co] + sum_k X[p][k] * W[co][k]
// A-operand: lane holds X[p0+(l&15)][k0+(l>>4)*8 + j] -> 16B contiguous load.
// B-operand: lane holds W[co0+nt*16+(l&15)][same k] -> 16B contiguous load (native layout).
// D: row p = p0+(l>>4)*4+r, col co = co0+nt*16+(l&15).
// EPI: 0 bf16 [p][CO]; 1 lrelu+bf16 [p][CO]; 2 fp32 vs-layout scatter; 3 fp32 [co][p] + residual
template <int K, int NT, int EPI>
__global__ __launch_bounds__(256) void k_gemm(const unsigned short* __restrict__ A,
                                              const unsigned short* __restrict__ W,
                                              const float* __restrict__ bias,
                                              void* __restrict__ outp,
                                              const float* __restrict__ aux, int CO) {
  int wv = threadIdx.x >> 6;
  int l = threadIdx.x & 63;
  int lm = l & 15, lq = l >> 4;
  int p0 = blockIdx.x * 64 + wv * 16;
  int co0 = blockIdx.y * (NT * 16);

  f32x4 acc[NT];
#pragma unroll
  for (int nt = 0; nt < NT; nt++) {
    float bv = bias[co0 + nt * 16 + lm];
    acc[nt] = (f32x4){bv, bv, bv, bv};
  }
  const unsigned short* ap = A + (size_t)(p0 + lm) * K + lq * 8;
  const unsigned short* wp = W + (size_t)(co0 + lm) * K + lq * 8;
#pragma unroll
  for (int k0 = 0; k0 < K; k0 += 32) {
    short8 af = *(const short8*)(ap + k0);
#pragma unroll
    for (int nt = 0; nt < NT; nt++) {
      short8 bf = *(const short8*)(wp + (size_t)nt * 16 * K + k0);
      acc[nt] = __builtin_amdgcn_mfma_f32_16x16x32_bf16(af, bf, acc[nt], 0, 0, 0);
    }
  }
#pragma unroll
  for (int nt = 0; nt < NT; nt++) {
    int co = co0 + nt * 16 + lm;
#pragma unroll
    for (int r = 0; r < 4; r++) {
      int p = p0 + lq * 4 + r;
      float v = acc[nt][r];
      if (EPI == 1) v = lrelu_f(v);
      if (EPI == 0 || EPI == 1) {
        ((unsigned short*)outp)[(size_t)p * CO + co] = f2bf(v);
      } else if (EPI == 2) {
        // vs layout [(co>>3)][p][co&7], co = t*64 + m*8 + d -> slot = t*8+m
        ((float*)outp)[((size_t)(co >> 3) * HWN + p) * 8 + (co & 7)] = v;
      } else {
        ((float*)outp)[(size_t)co * HWN + p] = v + aux[(size_t)co * HWN + p];
      }
    }
  }
}

// Fused softmax + deformable sampling; 8 lanes cooperate per (pixel, head).
// off/po/aw are bf16 in pixel-major rows; vs fp32 [(l*8+m)][p][8].
__global__ void k_msdeform(const float* __restrict__ vs, const unsigned short* __restrict__ offo,
                           const unsigned short* __restrict__ poo, const unsigned short* __restrict__ awo,
                           const float* __restrict__ flow1, const float* __restrict__ fcn2,
                           unsigned short* __restrict__ featb) {
  int yl = threadIdx.x & 7;
  int p = blockIdx.x * 32 + (threadIdx.x >> 3);
  int m = blockIdx.y;
  int px = p & 63, py = p >> 6;

  float fx1 = flow1[p], fy1 = flow1[HWN + p];
  float fx2 = fcn2[p],  fy2 = fcn2[HWN + p];

  float acc[8];
#pragma unroll
  for (int d = 0; d < 8; d++) acc[d] = 0.f;
  float wsum = 0.f;

  for (int pair = yl; pair < 36; pair += 8) {
    int l = pair / 12, pt = pair % 12;
    float fx = (l == 1) ? fx1 : ((l == 2) ? fx2 : 0.f);
    float fy = (l == 1) ? fy1 : ((l == 2) ? fy2 : 0.f);
    int ch = (m * 3 + l) * 12 + pt;
    unsigned ow = *(const unsigned*)(offo + (size_t)p * 576 + ch * 2);
    float ox = bf2f((unsigned short)(ow & 0xffff));
    float oy = bf2f((unsigned short)(ow >> 16));
    float s = 3.f / (1.f + __expf(-bf2f(poo[(size_t)p * 288 + ch])));
    float bx = (float)px + ox + fx;
    float by = (float)py + oy + fy;
    const float* vbase = vs + (size_t)(l * 8 + m) * HWN * 8;
    const unsigned short* lgp = awo + (size_t)p * 2592 + m * 324 + l * 108 + pt * 9;
#pragma unroll
    for (int kk = 0; kk < 9; kk++) {
      float pnx = (float)(kk / 3 - 1);
      float pny = (float)(kk % 3 - 1);
      float ix = bx + pnx * s;
      float iy = by + pny * s;
      float wgt = __expf(bf2f(lgp[kk]));
      wsum += wgt;

      float fx0 = floorf(ix), fy0 = floorf(iy);
      int x0 = (int)fx0, y0 = (int)fy0;
      float wx1 = ix - fx0, wy1 = iy - fy0;
      float wx0 = 1.f - wx1, wy0 = 1.f - wy1;

      float tw[4];
      int tx[4], ty[4];
      tw[0] = wx0 * wy0; tx[0] = x0;     ty[0] = y0;
      tw[1] = wx1 * wy0; tx[1] = x0 + 1; ty[1] = y0;
      tw[2] = wx0 * wy1; tx[2] = x0;     ty[2] = y0 + 1;
      tw[3] = wx1 * wy1; tx[3] = x0 + 1; ty[3] = y0 + 1;
#pragma unroll
      for (int t = 0; t < 4; t++) {
        if ((unsigned)tx[t] < 64u && (unsigned)ty[t] < 64u) {
          const float4* vp4 = (const float4*)(vbase + (size_t)(ty[t] * 64 + tx[t]) * 8);
          float4 a0 = vp4[0], a1 = vp4[1];
          float ww = wgt * tw[t];
          acc[0] += ww * a0.x; acc[1] += ww * a0.y; acc[2] += ww * a0.z; acc[3] += ww * a0.w;
          acc[4] += ww * a1.x; acc[5] += ww * a1.y; acc[6] += ww * a1.z; acc[7] += ww * a1.w;
        }
      }
    }
  }
#pragma unroll
  for (int mask = 1; mask < 8; mask <<= 1) {
    wsum += __shfl_xor(wsum, mask);
#pragma unroll
    for (int d = 0; d < 8; d++) acc[d] += __shfl_xor(acc[d], mask);
  }
  float inv = 1.f / wsum;
  float r = 0.f;
#pragma unroll
  for (int d = 0; d < 8; d++) r = (d == yl) ? acc[d] : r;
  featb[(size_t)p * 64 + m * 8 + yl] = f2bf(r * inv);
}

extern "C" void kernel_launch(void* const* d_in, const int* in_sizes, int n_in,
                              void* d_out, int out_size, void* d_ws, size_t ws_size,
                              hipStream_t stream) {
  const float* x     = (const float*)d_in[0];
  const float* flow1 = (const float*)d_in[1];
  const float* flow2 = (const float*)d_in[2];
  const float* aw_w1 = (const float*)d_in[5];
  const float* aw_b1 = (const float*)d_in[6];
  const float* aw_w2 = (const float*)d_in[7];
  const float* aw_b2 = (const float*)d_in[8];
  const float* aw_w3 = (const float*)d_in[9];
  const float* aw_b3 = (const float*)d_in[10];
  const float* aw_w4 = (const float*)d_in[11];
  const float* aw_b4 = (const float*)d_in[12];
  const float* so_w1 = (const float*)d_in[13];
  const float* so_b1 = (const float*)d_in[14];
  const float* so_w2 = (const float*)d_in[15];
  const float* so_b2 = (const float*)d_in[16];
  const float* so_w3 = (const float*)d_in[17];
  const float* so_b3 = (const float*)d_in[18];
  const float* so_w4 = (const float*)d_in[19];
  const float* so_b4 = (const float*)d_in[20];
  const float* po_w1 = (const float*)d_in[21];
  const float* po_b1 = (const float*)d_in[22];
  const float* po_w2 = (const float*)d_in[23];
  const float* po_b2 = (const float*)d_in[24];
  const float* po_w3 = (const float*)d_in[25];
  const float* po_b3 = (const float*)d_in[26];
  const float* po_w4 = (const float*)d_in[27];
  const float* po_b4 = (const float*)d_in[28];
  const float* vp_w  = (const float*)d_in[29];
  const float* vp_b  = (const float*)d_in[30];
  const float* op_w1 = (const float*)d_in[31];
  const float* op_b1 = (const float*)d_in[32];
  const float* op_w2 = (const float*)d_in[33];
  const float* op_b2 = (const float*)d_in[34];

  char* base = (char*)d_ws;
  size_t off = 0;
  auto alloc = [&](size_t bytes) { void* pp = base + off; off = (off + bytes + 255) & ~(size_t)255; return pp; };

  float* fcn2  = (float*)alloc(2 * HWN * 4);
  float* vs    = (float*)alloc(192 * HWN * 4);
  unsigned short* extra = (unsigned short*)alloc(224 * HWN * 2);
  unsigned short* xb    = (unsigned short*)alloc(192 * HWN * 2);
  unsigned short* tA    = (unsigned short*)alloc(64 * HWN * 2);
  unsigned short* tB    = (unsigned short*)alloc(64 * HWN * 2);
  unsigned short* X9    = (unsigned short*)alloc(576 * HWN * 2);
  unsigned short* off_o = (unsigned short*)alloc(576 * HWN * 2);
  unsigned short* po_o  = (unsigned short*)alloc(288 * HWN * 2);
  unsigned short* aw_o  = (unsigned short*)alloc((size_t)2592 * HWN * 2);
  unsigned short* featb = (unsigned short*)alloc(64 * HWN * 2);
  unsigned short* hopb  = (unsigned short*)alloc(64 * HWN * 2);
  unsigned short* awt  = (unsigned short*)alloc(2592 * 64 * 2);
  unsigned short* sot  = (unsigned short*)alloc(576 * 64 * 2);
  unsigned short* pot  = (unsigned short*)alloc(288 * 64 * 2);
  unsigned short* vpb  = (unsigned short*)alloc(192 * 192 * 2);
  unsigned short* o1b  = (unsigned short*)alloc(64 * 64 * 2);
  unsigned short* o2b  = (unsigned short*)alloc(64 * 64 * 2);
  unsigned short* awh  = (unsigned short*)alloc(64 * 224 * 2);
  unsigned short* soh  = (unsigned short*)alloc(64 * 224 * 2);
  unsigned short* poh  = (unsigned short*)alloc(64 * 224 * 2);
  unsigned short* awc2 = (unsigned short*)alloc(64 * 576 * 2);
  unsigned short* awc3 = (unsigned short*)alloc(64 * 576 * 2);
  unsigned short* soc2 = (unsigned short*)alloc(64 * 576 * 2);
  unsigned short* soc3 = (unsigned short*)alloc(64 * 576 * 2);
  unsigned short* poc2 = (unsigned short*)alloc(64 * 576 * 2);
  unsigned short* poc3 = (unsigned short*)alloc(64 * 576 * 2);

  k_wconv<<<dim3(648, 15), 256, 0, stream>>>(
      aw_w4, so_w4, po_w4, vp_w, op_w1, op_w2, aw_w1, so_w1, po_w1,
      aw_w2, aw_w3, so_w2, so_w3, po_w2, po_w3,
      awt, sot, pot, vpb, o1b, o2b, awh, soh, poh,
      awc2, awc3, soc2, soc3, poc2, poc3);

  k_flowcn2<<<16, 256, 0, stream>>>(flow1, flow2, fcn2);
  k_extra<<<dim3(16, 64), 256, 0, stream>>>(x, flow1, fcn2, extra, xb);

  // value projection 192->192, vs-layout epilogue
  k_gemm<192, 2, 2><<<dim3(64, 6), 256, 0, stream>>>(xb, vpb, vp_b, vs, nullptr, 192);

  // so trunk
  k_gemm<224, 1, 1><<<dim3(64, 4), 256, 0, stream>>>(extra, soh, so_b1, tA, nullptr, 64);
  k_im2col<<<1152, 256, 0, stream>>>(tA, X9);
  k_gemm<576, 1, 1><<<dim3(64, 4), 256, 0, stream>>>(X9, soc2, so_b2, tB, nullptr, 64);
  k_im2col<<<1152, 256, 0, stream>>>(tB, X9);
  k_gemm<576, 1, 1><<<dim3(64, 4), 256, 0, stream>>>(X9, soc3, so_b3, tA, nullptr, 64);
  k_gemm<64, 2, 0><<<dim3(64, 18), 256, 0, stream>>>(tA, sot, so_b4, off_o, nullptr, 576);

  // po trunk
  k_gemm<224, 1, 1><<<dim3(64, 4), 256, 0, stream>>>(extra, poh, po_b1, tA, nullptr, 64);
  k_im2col<<<1152, 256, 0, stream>>>(tA, X9);
  k_gemm<576, 1, 1><<<dim3(64, 4), 256, 0, stream>>>(X9, poc2, po_b2, tB, nullptr, 64);
  k_im2col<<<1152, 256, 0, stream>>>(tB, X9);
  k_gemm<576, 1, 1><<<dim3(64, 4), 256, 0, stream>>>(X9, poc3, po_b3, tA, nullptr, 64);
  k_gemm<64, 2, 0><<<dim3(64, 9), 256, 0, stream>>>(tA, pot, po_b4, po_o, nullptr, 288);

  // aw trunk
  k_gemm<224, 1, 1><<<dim3(64, 4), 256, 0, stream>>>(extra, awh, aw_b1, tA, nullptr, 64);
  k_im2col<<<1152, 256, 0, stream>>>(tA, X9);
  k_gemm<576, 1, 1><<<dim3(64, 4), 256, 0, stream>>>(X9, awc2, aw_b2, tB, nullptr, 64);
  k_im2col<<<1152, 256, 0, stream>>>(tB, X9);
  k_gemm<576, 1, 1><<<dim3(64, 4), 256, 0, stream>>>(X9, awc3, aw_b3, tA, nullptr, 64);
  k_gemm<64, 2, 0><<<dim3(64, 81), 256, 0, stream>>>(tA, awt, aw_b4, aw_o, nullptr, 2592);

  // fused softmax + deformable sampling
  k_msdeform<<<dim3(128, 8), 256, 0, stream>>>(vs, off_o, po_o, aw_o, flow1, fcn2, featb);

  // output convs
  k_gemm<64, 1, 1><<<dim3(64, 4), 256, 0, stream>>>(featb, o1b, op_b1, hopb, nullptr, 64);
  k_gemm<64, 1, 3><<<dim3(64, 4), 256, 0, stream>>>(hopb, o2b, op_b2, d_out, x, 64);
}

// Round 4
// 251.338 us; speedup vs baseline: 3.2803x; 1.2200x over previous
//
#include <hip/hip_runtime.h>
#include <hip/hip_bf16.h>
#include <math.h>

// Problem constants: n=1, t=3(=L), c=64, h=w=64, M=8 heads, D=8, P=12, KK=9
#define HWN 4096

typedef __attribute__((ext_vector_type(8))) short short8;   // 8 bf16 (4 VGPRs)
typedef __attribute__((ext_vector_type(4))) float f32x4;    // MFMA C/D

__device__ __forceinline__ float lrelu_f(float v) { return v >= 0.f ? v : 0.1f * v; }

__device__ __forceinline__ unsigned short f2bf(float f) {
  union { float f; unsigned u; } v; v.f = f;
  unsigned r = v.u + 0x7fff + ((v.u >> 16) & 1);   // round-to-nearest-even
  return (unsigned short)(r >> 16);
}
__device__ __forceinline__ float bf2f(unsigned short u) {
  union { unsigned u; float f; } v; v.u = ((unsigned)u) << 16;
  return v.f;
}
__device__ __forceinline__ float bf_lo(unsigned u) {
  union { unsigned u; float f; } v; v.u = u << 16; return v.f;
}
__device__ __forceinline__ float bf_hi(unsigned u) {
  union { unsigned u; float f; } v; v.u = u & 0xffff0000u; return v.f;
}

// bilinear sample with zeros padding (fp32 source)
__device__ __forceinline__ float bilin_zero(const float* __restrict__ img, float ix, float iy) {
  float fx0 = floorf(ix), fy0 = floorf(iy);
  int x0 = (int)fx0, y0 = (int)fy0;
  float wx1 = ix - fx0, wy1 = iy - fy0;
  float wx0 = 1.f - wx1, wy0 = 1.f - wy1;
  float acc = 0.f;
  if ((unsigned)y0 < 64u) {
    if ((unsigned)x0 < 64u)       acc += wx0 * wy0 * img[y0 * 64 + x0];
    if ((unsigned)(x0 + 1) < 64u) acc += wx1 * wy0 * img[y0 * 64 + x0 + 1];
  }
  if ((unsigned)(y0 + 1) < 64u) {
    if ((unsigned)x0 < 64u)       acc += wx0 * wy1 * img[(y0 + 1) * 64 + x0];
    if ((unsigned)(x0 + 1) < 64u) acc += wx1 * wy1 * img[(y0 + 1) * 64 + x0 + 1];
  }
  return acc;
}

// flow_cn2 = flow_1 + flow_warp(flow_2, flow_1)
__global__ void k_flowcn2(const float* __restrict__ flow1, const float* __restrict__ flow2,
                          float* __restrict__ fcn2) {
  int p = blockIdx.x * 256 + threadIdx.x;
  int x = p & 63, y = p >> 6;
  float fx = flow1[p], fy = flow1[HWN + p];
  float ix = (float)x + fx, iy = (float)y + fy;
  fcn2[p] = fx + bilin_zero(flow2, ix, iy);
  fcn2[HWN + p] = fy + bilin_zero(flow2 + HWN, ix, iy);
}

// extra[p][224] bf16 (196 real + 28 zero-pad) and xb[p][192] bf16 (value-proj input)
__global__ void k_extra(const float* __restrict__ x, const float* __restrict__ flow1,
                        const float* __restrict__ fcn2, unsigned short* __restrict__ extra,
                        unsigned short* __restrict__ xb) {
  int p = blockIdx.x * 256 + threadIdx.x;
  int c = blockIdx.y;  // 0..63
  int xx = p & 63, yy = p >> 6;
  float x0 = x[c * HWN + p];
  float x1 = x[(64 + c) * HWN + p];
  float x2 = x[(128 + c) * HWN + p];
  xb[p * 192 + c]        = f2bf(x0);
  xb[p * 192 + 64 + c]   = f2bf(x1);
  xb[p * 192 + 128 + c]  = f2bf(x2);
  extra[p * 224 + c] = f2bf(x0);
  float ix1 = (float)xx + flow1[p], iy1 = (float)yy + flow1[HWN + p];
  float ix2 = (float)xx + fcn2[p],  iy2 = (float)yy + fcn2[HWN + p];
  extra[p * 224 + 64 + c]  = f2bf(bilin_zero(x + (64 + c) * HWN, ix1, iy1));
  extra[p * 224 + 128 + c] = f2bf(bilin_zero(x + (128 + c) * HWN, ix2, iy2));
  if (c < 2) {
    extra[p * 224 + 192 + c] = f2bf(flow1[c * HWN + p]);
    extra[p * 224 + 194 + c] = f2bf(fcn2[c * HWN + p]);
  }
  if (c < 28) extra[p * 224 + 196 + c] = 0;
}

// Weight staging: fused/concatenated bf16 weights + concatenated fp32 biases.
// Trunk order everywhere: t=0 so, t=1 po, t=2 aw.
__global__ void k_wconv(
    const float* so_w4, const float* po_w4, const float* aw_w4,
    const float* so_b4, const float* po_b4, const float* aw_b4,
    const float* so_b1, const float* po_b1, const float* aw_b1,
    const float* so_b2, const float* po_b2, const float* aw_b2,
    const float* so_b3, const float* po_b3, const float* aw_b3,
    const float* so_w1, const float* po_w1, const float* aw_w1,
    const float* so_w2, const float* po_w2, const float* aw_w2,
    const float* so_w3, const float* po_w3, const float* aw_w3,
    const float* op_w1, const float* op_w2, const float* vp_w,
    unsigned short* Wtail, float* btail, float* b1c, float* b2c, float* b3c,
    unsigned short* o1b, unsigned short* o2b, unsigned short* W1,
    unsigned short* W2g, unsigned short* W3g, unsigned short* vpb) {
  int t = blockIdx.x * 256 + threadIdx.x;
  int y = blockIdx.y;
  if (y == 0) {  // Wtail [3456][64]: rows 0..575 so_w4, 576..863 po_w4, 864..3455 aw_w4
    if (t < 3456 * 64) {
      int row = t >> 6, k = t & 63;
      float v = row < 576 ? so_w4[row * 64 + k]
              : row < 864 ? po_w4[(row - 576) * 64 + k]
                          : aw_w4[(row - 864) * 64 + k];
      Wtail[t] = f2bf(v);
    }
  } else if (y == 1) {  // biases + small weight casts
    if (t < 3456) {
      btail[t] = t < 576 ? so_b4[t] : t < 864 ? po_b4[t - 576] : aw_b4[t - 864];
    } else if (t < 3648) {
      int i = t - 3456; b1c[i] = i < 64 ? so_b1[i] : i < 128 ? po_b1[i - 64] : aw_b1[i - 128];
    } else if (t < 3840) {
      int i = t - 3648; b2c[i] = i < 64 ? so_b2[i] : i < 128 ? po_b2[i - 64] : aw_b2[i - 128];
    } else if (t < 4032) {
      int i = t - 3840; b3c[i] = i < 64 ? so_b3[i] : i < 128 ? po_b3[i - 64] : aw_b3[i - 128];
    } else if (t < 8128) {
      o1b[t - 4032] = f2bf(op_w1[t - 4032]);
    } else if (t < 12224) {
      o2b[t - 8128] = f2bf(op_w2[t - 8128]);
    }
  } else if (y == 2) {  // W1 [192][224]: rows t*64+co from {so,po,aw}_w1 [64][196], zero-pad K
    if (t < 192 * 224) {
      int row = t / 224, k = t % 224;
      int tr = row >> 6, lco = row & 63;
      const float* s = tr == 0 ? so_w1 : tr == 1 ? po_w1 : aw_w1;
      W1[t] = (k < 196) ? f2bf(s[lco * 196 + k]) : (unsigned short)0;
    }
  } else if (y == 3 || y == 4) {  // W2g/W3g [3][64][576], k-order kidx*64+ci
    if (t < 3 * 64 * 576) {
      int tr = t / 36864, rem = t % 36864;
      int co = rem / 576, r2 = rem % 576;
      int kidx = r2 >> 6, ci = r2 & 63;
      const float* s;
      if (y == 3) s = tr == 0 ? so_w2 : tr == 1 ? po_w2 : aw_w2;
      else        s = tr == 0 ? so_w3 : tr == 1 ? po_w3 : aw_w3;
      (y == 3 ? W2g : W3g)[t] = f2bf(s[co * 576 + ci * 9 + kidx]);
    }
  } else {  // vpb [192][192] cast
    if (t < 192 * 192) vpb[t] = f2bf(vp_w[t]);
  }
}

// MFMA GEMM: C[p][co] = bias[co] + sum_k A[p][k] * W[co][k]
// EPI: 0 bf16 [p][LDC]; 1 lrelu+bf16 [p][LDC]; 2 bf16 vs-layout scatter; 3 fp32 [co][HWN] + residual
template <int K, int LDA, int NT, int EPI>
__global__ __launch_bounds__(256) void k_gemm(const unsigned short* __restrict__ A,
                                              const unsigned short* __restrict__ W,
                                              const float* __restrict__ bias,
                                              void* __restrict__ outp,
                                              const float* __restrict__ aux, int LDC) {
  int wv = threadIdx.x >> 6;
  int l = threadIdx.x & 63;
  int lm = l & 15, lq = l >> 4;
  int p0 = blockIdx.x * 64 + wv * 16;
  int co0 = blockIdx.y * (NT * 16);

  f32x4 acc[NT];
#pragma unroll
  for (int nt = 0; nt < NT; nt++) {
    float bv = bias[co0 + nt * 16 + lm];
    acc[nt] = (f32x4){bv, bv, bv, bv};
  }
  const unsigned short* ap = A + (size_t)(p0 + lm) * LDA + lq * 8;
  const unsigned short* wp = W + (size_t)(co0 + lm) * K + lq * 8;
#pragma unroll
  for (int k0 = 0; k0 < K; k0 += 32) {
    short8 af = *(const short8*)(ap + k0);
#pragma unroll
    for (int nt = 0; nt < NT; nt++) {
      short8 bf = *(const short8*)(wp + (size_t)nt * 16 * K + k0);
      acc[nt] = __builtin_amdgcn_mfma_f32_16x16x32_bf16(af, bf, acc[nt], 0, 0, 0);
    }
  }
#pragma unroll
  for (int nt = 0; nt < NT; nt++) {
    int co = co0 + nt * 16 + lm;
#pragma unroll
    for (int r = 0; r < 4; r++) {
      int p = p0 + lq * 4 + r;
      float v = acc[nt][r];
      if (EPI == 1) v = lrelu_f(v);
      if (EPI == 0 || EPI == 1) {
        ((unsigned short*)outp)[(size_t)p * LDC + co] = f2bf(v);
      } else if (EPI == 2) {
        // vs layout [(co>>3)][p][co&7], co = t*64+m*8+d -> slot t*8+m
        ((unsigned short*)outp)[((size_t)(co >> 3) * HWN + p) * 8 + (co & 7)] = f2bf(v);
      } else {
        ((float*)outp)[(size_t)co * HWN + p] = v + aux[(size_t)co * HWN + p];
      }
    }
  }
}

// Grouped direct 3x3 conv (pad 1) as MFMA GEMM over shifted rows of h [p][192].
// z = trunk; reads cols t*64..t*64+63, writes lrelu bf16 out[p][192] same cols.
__global__ __launch_bounds__(256) void k_conv3g(const unsigned short* __restrict__ h,
                                                const unsigned short* __restrict__ W,
                                                const float* __restrict__ bias,
                                                unsigned short* __restrict__ out) {
  int wv = threadIdx.x >> 6;
  int l = threadIdx.x & 63;
  int lm = l & 15, lq = l >> 4;
  int p0 = blockIdx.x * 64 + wv * 16;
  int co0 = blockIdx.y * 16;
  int t = blockIdx.z;
  int p = p0 + lm;
  int px = p & 63, py = p >> 6;

  float bv = bias[t * 64 + co0 + lm];
  f32x4 acc = (f32x4){bv, bv, bv, bv};
  const unsigned short* wp = W + ((size_t)t * 64 + co0 + lm) * 576 + lq * 8;
#pragma unroll
  for (int kidx = 0; kidx < 9; kidx++) {
    int ky = kidx / 3, kx = kidx % 3;
    int pp = p + (ky - 1) * 64 + (kx - 1);
    bool valid = ((unsigned)(px + kx - 1) < 64u) && ((unsigned)(py + ky - 1) < 64u);
    const unsigned short* apb = h + (size_t)pp * 192 + t * 64 + lq * 8;
#pragma unroll
    for (int c2 = 0; c2 < 2; c2++) {
      short8 af = {};
      if (valid) af = *(const short8*)(apb + c2 * 32);
      short8 bf = *(const short8*)(wp + kidx * 64 + c2 * 32);
      acc = __builtin_amdgcn_mfma_f32_16x16x32_bf16(af, bf, acc, 0, 0, 0);
    }
  }
#pragma unroll
  for (int r = 0; r < 4; r++) {
    int po_ = p0 + lq * 4 + r;
    out[(size_t)po_ * 192 + t * 64 + co0 + lm] = f2bf(lrelu_f(acc[r]));
  }
}

// Fused tail GEMM: all three trunk 1x1 tails in one launch.
// A = h3 [p][192] (col offset trunk*64), W = Wtail [3456][64], out bf16 [p][3456].
__global__ __launch_bounds__(256) void k_tail(const unsigned short* __restrict__ A,
                                              const unsigned short* __restrict__ W,
                                              const float* __restrict__ bias,
                                              unsigned short* __restrict__ out) {
  int wv = threadIdx.x >> 6;
  int l = threadIdx.x & 63;
  int lm = l & 15, lq = l >> 4;
  int p0 = blockIdx.x * 64 + wv * 16;
  int co0 = blockIdx.y * 32;
  int t = (co0 < 576) ? 0 : (co0 < 864 ? 1 : 2);

  f32x4 acc[2];
#pragma unroll
  for (int nt = 0; nt < 2; nt++) {
    float bv = bias[co0 + nt * 16 + lm];
    acc[nt] = (f32x4){bv, bv, bv, bv};
  }
  const unsigned short* ap = A + (size_t)(p0 + lm) * 192 + t * 64 + lq * 8;
  const unsigned short* wp = W + (size_t)(co0 + lm) * 64 + lq * 8;
#pragma unroll
  for (int k0 = 0; k0 < 64; k0 += 32) {
    short8 af = *(const short8*)(ap + k0);
#pragma unroll
    for (int nt = 0; nt < 2; nt++) {
      short8 bf = *(const short8*)(wp + (size_t)nt * 16 * 64 + k0);
      acc[nt] = __builtin_amdgcn_mfma_f32_16x16x32_bf16(af, bf, acc[nt], 0, 0, 0);
    }
  }
#pragma unroll
  for (int nt = 0; nt < 2; nt++) {
    int co = co0 + nt * 16 + lm;
#pragma unroll
    for (int r = 0; r < 4; r++) {
      int p = p0 + lq * 4 + r;
      out[(size_t)p * 3456 + co] = f2bf(acc[nt][r]);
    }
  }
}

// Fused softmax + deformable sampling; 16 lanes cooperate per (pixel, head).
// to [p][3456]: cols 0..575 off, 576..863 po, 864..3455 aw. vsb bf16 [(l*8+m)][p][8].
__global__ void k_msdeform(const unsigned short* __restrict__ vsb,
                           const unsigned short* __restrict__ to,
                           const float* __restrict__ flow1, const float* __restrict__ fcn2,
                           unsigned short* __restrict__ featb) {
  int yl = threadIdx.x & 15;
  int p = blockIdx.x * 16 + (threadIdx.x >> 4);
  int m = blockIdx.y;
  int px = p & 63, py = p >> 6;

  float fx1 = flow1[p], fy1 = flow1[HWN + p];
  float fx2 = fcn2[p],  fy2 = fcn2[HWN + p];

  const unsigned short* row = to + (size_t)p * 3456;

  float acc[8];
#pragma unroll
  for (int d = 0; d < 8; d++) acc[d] = 0.f;
  float wsum = 0.f;

  for (int pair = yl; pair < 36; pair += 16) {
    int l = pair / 12, pt = pair % 12;
    float fx = (l == 1) ? fx1 : ((l == 2) ? fx2 : 0.f);
    float fy = (l == 1) ? fy1 : ((l == 2) ? fy2 : 0.f);
    int ch = (m * 3 + l) * 12 + pt;
    unsigned ow = *(const unsigned*)(row + ch * 2);
    float ox = bf_lo(ow);
    float oy = bf_hi(ow);
    float s = 3.f / (1.f + __expf(-bf2f(row[576 + ch])));
    float bx = (float)px + ox + fx;
    float by = (float)py + oy + fy;
    const unsigned short* vbase = vsb + (size_t)(l * 8 + m) * HWN * 8;
    const unsigned short* lgp = row + 864 + m * 324 + l * 108 + pt * 9;
#pragma unroll
    for (int kk = 0; kk < 9; kk++) {
      float pnx = (float)(kk / 3 - 1);
      float pny = (float)(kk % 3 - 1);
      float ix = bx + pnx * s;
      float iy = by + pny * s;
      float wgt = __expf(bf2f(lgp[kk]));
      wsum += wgt;

      float fx0 = floorf(ix), fy0 = floorf(iy);
      int x0 = (int)fx0, y0 = (int)fy0;
      float wx1 = ix - fx0, wy1 = iy - fy0;
      float wx0 = 1.f - wx1, wy0 = 1.f - wy1;

      float tw[4];
      int tx[4], ty[4];
      tw[0] = wx0 * wy0; tx[0] = x0;     ty[0] = y0;
      tw[1] = wx1 * wy0; tx[1] = x0 + 1; ty[1] = y0;
      tw[2] = wx0 * wy1; tx[2] = x0;     ty[2] = y0 + 1;
      tw[3] = wx1 * wy1; tx[3] = x0 + 1; ty[3] = y0 + 1;
#pragma unroll
      for (int c = 0; c < 4; c++) {
        if ((unsigned)tx[c] < 64u && (unsigned)ty[c] < 64u) {
          uint4 uv = *(const uint4*)(vbase + (size_t)(ty[c] * 64 + tx[c]) * 8);
          float ww = wgt * tw[c];
          acc[0] += ww * bf_lo(uv.x); acc[1] += ww * bf_hi(uv.x);
          acc[2] += ww * bf_lo(uv.y); acc[3] += ww * bf_hi(uv.y);
          acc[4] += ww * bf_lo(uv.z); acc[5] += ww * bf_hi(uv.z);
          acc[6] += ww * bf_lo(uv.w); acc[7] += ww * bf_hi(uv.w);
        }
      }
    }
  }
#pragma unroll
  for (int mask = 1; mask < 16; mask <<= 1) {
    wsum += __shfl_xor(wsum, mask);
#pragma unroll
    for (int d = 0; d < 8; d++) acc[d] += __shfl_xor(acc[d], mask);
  }
  if (yl < 8) {
    float inv = 1.f / wsum;
    float r = 0.f;
#pragma unroll
    for (int d = 0; d < 8; d++) r = (d == yl) ? acc[d] : r;
    featb[(size_t)p * 64 + m * 8 + yl] = f2bf(r * inv);
  }
}

extern "C" void kernel_launch(void* const* d_in, const int* in_sizes, int n_in,
                              void* d_out, int out_size, void* d_ws, size_t ws_size,
                              hipStream_t stream) {
  const float* x     = (const float*)d_in[0];
  const float* flow1 = (const float*)d_in[1];
  const float* flow2 = (const float*)d_in[2];
  const float* aw_w1 = (const float*)d_in[5];
  const float* aw_b1 = (const float*)d_in[6];
  const float* aw_w2 = (const float*)d_in[7];
  const float* aw_b2 = (const float*)d_in[8];
  const float* aw_w3 = (const float*)d_in[9];
  const float* aw_b3 = (const float*)d_in[10];
  const float* aw_w4 = (const float*)d_in[11];
  const float* aw_b4 = (const float*)d_in[12];
  const float* so_w1 = (const float*)d_in[13];
  const float* so_b1 = (const float*)d_in[14];
  const float* so_w2 = (const float*)d_in[15];
  const float* so_b2 = (const float*)d_in[16];
  const float* so_w3 = (const float*)d_in[17];
  const float* so_b3 = (const float*)d_in[18];
  const float* so_w4 = (const float*)d_in[19];
  const float* so_b4 = (const float*)d_in[20];
  const float* po_w1 = (const float*)d_in[21];
  const float* po_b1 = (const float*)d_in[22];
  const float* po_w2 = (const float*)d_in[23];
  const float* po_b2 = (const float*)d_in[24];
  const float* po_w3 = (const float*)d_in[25];
  const float* po_b3 = (const float*)d_in[26];
  const float* po_w4 = (const float*)d_in[27];
  const float* po_b4 = (const float*)d_in[28];
  const float* vp_w  = (const float*)d_in[29];
  const float* vp_b  = (const float*)d_in[30];
  const float* op_w1 = (const float*)d_in[31];
  const float* op_b1 = (const float*)d_in[32];
  const float* op_w2 = (const float*)d_in[33];
  const float* op_b2 = (const float*)d_in[34];

  char* base = (char*)d_ws;
  size_t off = 0;
  auto alloc = [&](size_t bytes) { void* pp = base + off; off = (off + bytes + 255) & ~(size_t)255; return pp; };

  float* fcn2  = (float*)alloc(2 * HWN * 4);
  unsigned short* vsb   = (unsigned short*)alloc(192 * HWN * 2);
  unsigned short* extra = (unsigned short*)alloc(224 * HWN * 2);
  unsigned short* xb    = (unsigned short*)alloc(192 * HWN * 2);
  unsigned short* h1    = (unsigned short*)alloc(192 * HWN * 2);
  unsigned short* h2    = (unsigned short*)alloc(192 * HWN * 2);
  unsigned short* h3    = (unsigned short*)alloc(192 * HWN * 2);
  unsigned short* to    = (unsigned short*)alloc((size_t)3456 * HWN * 2);
  unsigned short* featb = (unsigned short*)alloc(64 * HWN * 2);
  unsigned short* hopb  = (unsigned short*)alloc(64 * HWN * 2);
  unsigned short* Wtail = (unsigned short*)alloc(3456 * 64 * 2);
  float* btail = (float*)alloc(3456 * 4);
  float* b1c   = (float*)alloc(192 * 4);
  float* b2c   = (float*)alloc(192 * 4);
  float* b3c   = (float*)alloc(192 * 4);
  unsigned short* o1b = (unsigned short*)alloc(64 * 64 * 2);
  unsigned short* o2b = (unsigned short*)alloc(64 * 64 * 2);
  unsigned short* W1  = (unsigned short*)alloc(192 * 224 * 2);
  unsigned short* W2g = (unsigned short*)alloc(3 * 64 * 576 * 2);
  unsigned short* W3g = (unsigned short*)alloc(3 * 64 * 576 * 2);
  unsigned short* vpb = (unsigned short*)alloc(192 * 192 * 2);

  k_wconv<<<dim3(864, 6), 256, 0, stream>>>(
      so_w4, po_w4, aw_w4, so_b4, po_b4, aw_b4,
      so_b1, po_b1, aw_b1, so_b2, po_b2, aw_b2, so_b3, po_b3, aw_b3,
      so_w1, po_w1, aw_w1, so_w2, po_w2, aw_w2, so_w3, po_w3, aw_w3,
      op_w1, op_w2, vp_w,
      Wtail, btail, b1c, b2c, b3c, o1b, o2b, W1, W2g, W3g, vpb);

  k_flowcn2<<<16, 256, 0, stream>>>(flow1, flow2, fcn2);
  k_extra<<<dim3(16, 64), 256, 0, stream>>>(x, flow1, fcn2, extra, xb);

  // value projection 192->192, bf16 vs-layout epilogue
  k_gemm<192, 192, 2, 2><<<dim3(64, 6), 256, 0, stream>>>(xb, vpb, vp_b, vsb, nullptr, 192);

  // fused trunk pipeline (so|po|aw in one [p][192] activation tensor)
  k_gemm<224, 224, 1, 1><<<dim3(64, 12), 256, 0, stream>>>(extra, W1, b1c, h1, nullptr, 192);
  k_conv3g<<<dim3(64, 4, 3), 256, 0, stream>>>(h1, W2g, b2c, h2);
  k_conv3g<<<dim3(64, 4, 3), 256, 0, stream>>>(h2, W3g, b3c, h3);
  k_tail<<<dim3(64, 108), 256, 0, stream>>>(h3, Wtail, btail, to);

  // fused softmax + deformable sampling (16 lanes per pixel-head, 32 waves/CU)
  k_msdeform<<<dim3(256, 8), 256, 0, stream>>>(vsb, to, flow1, fcn2, featb);

  // output convs
  k_gemm<64, 64, 1, 1><<<dim3(64, 4), 256, 0, stream>>>(featb, o1b, op_b1, hopb, nullptr, 64);
  k_gemm<64, 64, 1, 3><<<dim3(64, 4), 256, 0, stream>>>(hopb, o2b, op_b2, d_out, x, 64);
}

// Round 5
// 242.158 us; speedup vs baseline: 3.4046x; 1.0379x over previous
//
#include <hip/hip_runtime.h>
#include <hip/hip_bf16.h>
#include <math.h>

// Problem constants: n=1, t=3(=L), c=64, h=w=64, M=8 heads, D=8, P=12, KK=9
#define HWN 4096

typedef __attribute__((ext_vector_type(8))) short short8;   // 8 bf16 (4 VGPRs)
typedef __attribute__((ext_vector_type(4))) float f32x4;    // MFMA C/D

__device__ __forceinline__ float lrelu_f(float v) { return v >= 0.f ? v : 0.1f * v; }

__device__ __forceinline__ unsigned short f2bf(float f) {
  union { float f; unsigned u; } v; v.f = f;
  unsigned r = v.u + 0x7fff + ((v.u >> 16) & 1);   // round-to-nearest-even
  return (unsigned short)(r >> 16);
}
__device__ __forceinline__ float bf2f(unsigned short u) {
  union { unsigned u; float f; } v; v.u = ((unsigned)u) << 16;
  return v.f;
}
__device__ __forceinline__ float bf_lo(unsigned u) {
  union { unsigned u; float f; } v; v.u = u << 16; return v.f;
}
__device__ __forceinline__ float bf_hi(unsigned u) {
  union { unsigned u; float f; } v; v.u = u & 0xffff0000u; return v.f;
}

// bilinear sample with zeros padding (fp32 source)
__device__ __forceinline__ float bilin_zero(const float* __restrict__ img, float ix, float iy) {
  float fx0 = floorf(ix), fy0 = floorf(iy);
  int x0 = (int)fx0, y0 = (int)fy0;
  float wx1 = ix - fx0, wy1 = iy - fy0;
  float wx0 = 1.f - wx1, wy0 = 1.f - wy1;
  float acc = 0.f;
  if ((unsigned)y0 < 64u) {
    if ((unsigned)x0 < 64u)       acc += wx0 * wy0 * img[y0 * 64 + x0];
    if ((unsigned)(x0 + 1) < 64u) acc += wx1 * wy0 * img[y0 * 64 + x0 + 1];
  }
  if ((unsigned)(y0 + 1) < 64u) {
    if ((unsigned)x0 < 64u)       acc += wx0 * wy1 * img[(y0 + 1) * 64 + x0];
    if ((unsigned)(x0 + 1) < 64u) acc += wx1 * wy1 * img[(y0 + 1) * 64 + x0 + 1];
  }
  return acc;
}

// k_pre: all input-chain-independent prep in one launch.
// blocks [0,5184): weight staging; [5184,5376): x transpose -> xb [p][192] bf16;
// [5376,5392): flow_cn2.
__global__ void k_pre(
    const float* __restrict__ x, const float* __restrict__ flow1, const float* __restrict__ flow2,
    const float* so_w4, const float* po_w4, const float* aw_w4,
    const float* so_b4, const float* po_b4, const float* aw_b4,
    const float* so_b1, const float* po_b1, const float* aw_b1,
    const float* so_b2, const float* po_b2, const float* aw_b2,
    const float* so_b3, const float* po_b3, const float* aw_b3,
    const float* so_w1, const float* po_w1, const float* aw_w1,
    const float* so_w2, const float* po_w2, const float* aw_w2,
    const float* so_w3, const float* po_w3, const float* aw_w3,
    const float* op_w1, const float* op_w2, const float* vp_w,
    unsigned short* Wtail, float* btail, float* b1c, float* b2c, float* b3c,
    unsigned short* o1b, unsigned short* o2b, unsigned short* W1,
    unsigned short* W2g, unsigned short* W3g, unsigned short* vpb,
    unsigned short* xb, float* fcn2) {
  __shared__ unsigned short tile[64 * 65];
  int gx = blockIdx.x;
  int tid = threadIdx.x;
  if (gx < 5184) {
    int y = gx / 864;
    int t = (gx % 864) * 256 + tid;
    if (y == 0) {  // Wtail [3456][64]
      if (t < 3456 * 64) {
        int row = t >> 6, k = t & 63;
        float v = row < 576 ? so_w4[row * 64 + k]
                : row < 864 ? po_w4[(row - 576) * 64 + k]
                            : aw_w4[(row - 864) * 64 + k];
        Wtail[t] = f2bf(v);
      }
    } else if (y == 1) {  // biases + small weights
      if (t < 3456) {
        btail[t] = t < 576 ? so_b4[t] : t < 864 ? po_b4[t - 576] : aw_b4[t - 864];
      } else if (t < 3648) {
        int i = t - 3456; b1c[i] = i < 64 ? so_b1[i] : i < 128 ? po_b1[i - 64] : aw_b1[i - 128];
      } else if (t < 3840) {
        int i = t - 3648; b2c[i] = i < 64 ? so_b2[i] : i < 128 ? po_b2[i - 64] : aw_b2[i - 128];
      } else if (t < 4032) {
        int i = t - 3840; b3c[i] = i < 64 ? so_b3[i] : i < 128 ? po_b3[i - 64] : aw_b3[i - 128];
      } else if (t < 8128) {
        o1b[t - 4032] = f2bf(op_w1[t - 4032]);
      } else if (t < 12224) {
        o2b[t - 8128] = f2bf(op_w2[t - 8128]);
      }
    } else if (y == 2) {  // W1 [192][224] zero-padded K
      if (t < 192 * 224) {
        int row = t / 224, k = t % 224;
        int tr = row >> 6, lco = row & 63;
        const float* s = tr == 0 ? so_w1 : tr == 1 ? po_w1 : aw_w1;
        W1[t] = (k < 196) ? f2bf(s[lco * 196 + k]) : (unsigned short)0;
      }
    } else if (y == 3 || y == 4) {  // W2g/W3g [3][64][576], k-order kidx*64+ci
      if (t < 3 * 64 * 576) {
        int tr = t / 36864, rem = t % 36864;
        int co = rem / 576, r2 = rem % 576;
        int kidx = r2 >> 6, ci = r2 & 63;
        const float* s;
        if (y == 3) s = tr == 0 ? so_w2 : tr == 1 ? po_w2 : aw_w2;
        else        s = tr == 0 ? so_w3 : tr == 1 ? po_w3 : aw_w3;
        (y == 3 ? W2g : W3g)[t] = f2bf(s[co * 576 + ci * 9 + kidx]);
      }
    } else {  // vpb [192][192]
      if (t < 192 * 192) vpb[t] = f2bf(vp_w[t]);
    }
  } else if (gx < 5376) {  // transpose: 64-px tile x 64-ch group
    int b = gx - 5184;
    int ptile = b & 63, cg = b >> 6;  // 64 x 3
    int px = tid & 63, ch0 = (tid >> 6) * 16;
#pragma unroll
    for (int i = 0; i < 16; i++) {
      float v = x[(size_t)(cg * 64 + ch0 + i) * HWN + ptile * 64 + px];
      tile[(ch0 + i) * 65 + px] = f2bf(v);
    }
    __syncthreads();
    int c = tid & 63, pl0 = (tid >> 6) * 16;
#pragma unroll
    for (int i = 0; i < 16; i++)
      xb[(size_t)(ptile * 64 + pl0 + i) * 192 + cg * 64 + c] = tile[c * 65 + pl0 + i];
  } else {  // flow_cn2
    int p = (gx - 5376) * 256 + tid;
    int px = p & 63, py = p >> 6;
    float fx = flow1[p], fy = flow1[HWN + p];
    float ix = (float)px + fx, iy = (float)py + fy;
    fcn2[p] = fx + bilin_zero(flow2, ix, iy);
    fcn2[HWN + p] = fy + bilin_zero(flow2 + HWN, ix, iy);
  }
}

// k_extra: wave per pixel, lane = channel. All accesses coalesced.
__global__ void k_extra(const unsigned short* __restrict__ xb, const float* __restrict__ flow1,
                        const float* __restrict__ fcn2, unsigned short* __restrict__ extra) {
  int w = threadIdx.x >> 6, c = threadIdx.x & 63;
  int p = blockIdx.x * 4 + w;
  int px = p & 63, py = p >> 6;
  float fx1 = flow1[p], fy1 = flow1[HWN + p];
  float fx2 = fcn2[p],  fy2 = fcn2[HWN + p];
  extra[(size_t)p * 224 + c] = xb[(size_t)p * 192 + c];
#pragma unroll
  for (int lev = 0; lev < 2; lev++) {
    float ix = (float)px + (lev ? fx2 : fx1);
    float iy = (float)py + (lev ? fy2 : fy1);
    float fx0 = floorf(ix), fy0 = floorf(iy);
    int x0 = (int)fx0, y0 = (int)fy0;
    float wx1 = ix - fx0, wy1 = iy - fy0;
    float wx0 = 1.f - wx1, wy0 = 1.f - wy1;
    int coff = (lev + 1) * 64;
    float acc = 0.f;
    if ((unsigned)y0 < 64u) {
      if ((unsigned)x0 < 64u)       acc += wx0 * wy0 * bf2f(xb[(size_t)(y0 * 64 + x0) * 192 + coff + c]);
      if ((unsigned)(x0 + 1) < 64u) acc += wx1 * wy0 * bf2f(xb[(size_t)(y0 * 64 + x0 + 1) * 192 + coff + c]);
    }
    if ((unsigned)(y0 + 1) < 64u) {
      if ((unsigned)x0 < 64u)       acc += wx0 * wy1 * bf2f(xb[(size_t)((y0 + 1) * 64 + x0) * 192 + coff + c]);
      if ((unsigned)(x0 + 1) < 64u) acc += wx1 * wy1 * bf2f(xb[(size_t)((y0 + 1) * 64 + x0 + 1) * 192 + coff + c]);
    }
    extra[(size_t)p * 224 + coff + c] = f2bf(acc);
  }
  if (c < 2) {
    extra[(size_t)p * 224 + 192 + c] = f2bf(flow1[c * HWN + p]);
    extra[(size_t)p * 224 + 194 + c] = f2bf(fcn2[c * HWN + p]);
  }
  if (c < 28) extra[(size_t)p * 224 + 196 + c] = 0;
}

// Two GEMMs in one dispatch (blockIdx.z): z=0 value-proj (K=192, no act),
// z=1 trunk head (K=224, lrelu). Both: NT=4, out bf16 [p][192].
__global__ __launch_bounds__(256) void k_gemm2(
    const unsigned short* __restrict__ A0, const unsigned short* __restrict__ Wm0,
    const float* __restrict__ bias0, unsigned short* __restrict__ out0,
    const unsigned short* __restrict__ A1, const unsigned short* __restrict__ Wm1,
    const float* __restrict__ bias1, unsigned short* __restrict__ out1) {
  int z = blockIdx.z;
  const unsigned short* A = z ? A1 : A0;
  const unsigned short* Wm = z ? Wm1 : Wm0;
  const float* bias = z ? bias1 : bias0;
  unsigned short* out = z ? out1 : out0;
  int K = z ? 224 : 192;

  int wv = threadIdx.x >> 6;
  int l = threadIdx.x & 63;
  int lm = l & 15, lq = l >> 4;
  int p0 = blockIdx.x * 64 + wv * 16;
  int co0 = blockIdx.y * 64;

  f32x4 acc[4];
#pragma unroll
  for (int nt = 0; nt < 4; nt++) {
    float bv = bias[co0 + nt * 16 + lm];
    acc[nt] = (f32x4){bv, bv, bv, bv};
  }
  const unsigned short* ap = A + (size_t)(p0 + lm) * K + lq * 8;
  const unsigned short* wp = Wm + (size_t)(co0 + lm) * K + lq * 8;
  for (int k0 = 0; k0 < K; k0 += 32) {
    short8 af = *(const short8*)(ap + k0);
#pragma unroll
    for (int nt = 0; nt < 4; nt++) {
      short8 bf = *(const short8*)(wp + (size_t)nt * 16 * K + k0);
      acc[nt] = __builtin_amdgcn_mfma_f32_16x16x32_bf16(af, bf, acc[nt], 0, 0, 0);
    }
  }
#pragma unroll
  for (int nt = 0; nt < 4; nt++) {
    int co = co0 + nt * 16 + lm;
#pragma unroll
    for (int r = 0; r < 4; r++) {
      int p = p0 + lq * 4 + r;
      float v = acc[nt][r];
      if (z) v = lrelu_f(v);
      out[(size_t)p * 192 + co] = f2bf(v);
    }
  }
}

// Grouped direct 3x3 conv (pad 1) as MFMA GEMM over shifted rows of h [p][192]. NT=2 co.
__global__ __launch_bounds__(256) void k_conv3g(const unsigned short* __restrict__ h,
                                                const unsigned short* __restrict__ Wm,
                                                const float* __restrict__ bias,
                                                unsigned short* __restrict__ out) {
  int wv = threadIdx.x >> 6;
  int l = threadIdx.x & 63;
  int lm = l & 15, lq = l >> 4;
  int p0 = blockIdx.x * 64 + wv * 16;
  int co0 = blockIdx.y * 32;
  int t = blockIdx.z;
  int p = p0 + lm;
  int px = p & 63, py = p >> 6;

  f32x4 acc[2];
#pragma unroll
  for (int nt = 0; nt < 2; nt++) {
    float bv = bias[t * 64 + co0 + nt * 16 + lm];
    acc[nt] = (f32x4){bv, bv, bv, bv};
  }
  const unsigned short* wp = Wm + ((size_t)t * 64 + co0 + lm) * 576 + lq * 8;
#pragma unroll
  for (int kidx = 0; kidx < 9; kidx++) {
    int ky = kidx / 3, kx = kidx % 3;
    int pp = p + (ky - 1) * 64 + (kx - 1);
    bool valid = ((unsigned)(px + kx - 1) < 64u) && ((unsigned)(py + ky - 1) < 64u);
    const unsigned short* apb = h + (size_t)pp * 192 + t * 64 + lq * 8;
#pragma unroll
    for (int c2 = 0; c2 < 2; c2++) {
      short8 af = {};
      if (valid) af = *(const short8*)(apb + c2 * 32);
#pragma unroll
      for (int nt = 0; nt < 2; nt++) {
        short8 bf = *(const short8*)(wp + (size_t)nt * 16 * 576 + kidx * 64 + c2 * 32);
        acc[nt] = __builtin_amdgcn_mfma_f32_16x16x32_bf16(af, bf, acc[nt], 0, 0, 0);
      }
    }
  }
#pragma unroll
  for (int nt = 0; nt < 2; nt++) {
#pragma unroll
    for (int r = 0; r < 4; r++) {
      int po_ = p0 + lq * 4 + r;
      out[(size_t)po_ * 192 + t * 64 + co0 + nt * 16 + lm] = f2bf(lrelu_f(acc[nt][r]));
    }
  }
}

// Fused tail GEMM: all three trunk 1x1 tails. A = h3 [p][192] (col offset t*64),
// W = Wtail [3456][64], out bf16 [p][3456]. NT=2 (32-co tiles never cross trunks).
__global__ __launch_bounds__(256) void k_tail(const unsigned short* __restrict__ A,
                                              const unsigned short* __restrict__ Wm,
                                              const float* __restrict__ bias,
                                              unsigned short* __restrict__ out) {
  int wv = threadIdx.x >> 6;
  int l = threadIdx.x & 63;
  int lm = l & 15, lq = l >> 4;
  int p0 = blockIdx.x * 64 + wv * 16;
  int co0 = blockIdx.y * 32;
  int t = (co0 < 576) ? 0 : (co0 < 864 ? 1 : 2);

  f32x4 acc[2];
#pragma unroll
  for (int nt = 0; nt < 2; nt++) {
    float bv = bias[co0 + nt * 16 + lm];
    acc[nt] = (f32x4){bv, bv, bv, bv};
  }
  const unsigned short* ap = A + (size_t)(p0 + lm) * 192 + t * 64 + lq * 8;
  const unsigned short* wp = Wm + (size_t)(co0 + lm) * 64 + lq * 8;
#pragma unroll
  for (int k0 = 0; k0 < 64; k0 += 32) {
    short8 af = *(const short8*)(ap + k0);
#pragma unroll
    for (int nt = 0; nt < 2; nt++) {
      short8 bf = *(const short8*)(wp + (size_t)nt * 16 * 64 + k0);
      acc[nt] = __builtin_amdgcn_mfma_f32_16x16x32_bf16(af, bf, acc[nt], 0, 0, 0);
    }
  }
#pragma unroll
  for (int nt = 0; nt < 2; nt++) {
    int co = co0 + nt * 16 + lm;
#pragma unroll
    for (int r = 0; r < 4; r++) {
      int p = p0 + lq * 4 + r;
      out[(size_t)p * 3456 + co] = f2bf(acc[nt][r]);
    }
  }
}

// Fused softmax + deformable sampling; 16 lanes cooperate per (pixel, head).
// to [p][3456]: cols 0..575 off, 576..863 po, 864..3455 aw. vsb bf16 [p][192].
__global__ void k_msdeform(const unsigned short* __restrict__ vsb,
                           const unsigned short* __restrict__ to,
                           const float* __restrict__ flow1, const float* __restrict__ fcn2,
                           unsigned short* __restrict__ featb) {
  int yl = threadIdx.x & 15;
  int p = blockIdx.x * 16 + (threadIdx.x >> 4);
  int m = blockIdx.y;
  int px = p & 63, py = p >> 6;

  float fx1 = flow1[p], fy1 = flow1[HWN + p];
  float fx2 = fcn2[p],  fy2 = fcn2[HWN + p];

  const unsigned short* row = to + (size_t)p * 3456;

  float acc[8];
#pragma unroll
  for (int d = 0; d < 8; d++) acc[d] = 0.f;
  float wsum = 0.f;

  for (int pair = yl; pair < 36; pair += 16) {
    int l = pair / 12, pt = pair % 12;
    float fx = (l == 1) ? fx1 : ((l == 2) ? fx2 : 0.f);
    float fy = (l == 1) ? fy1 : ((l == 2) ? fy2 : 0.f);
    int ch = (m * 3 + l) * 12 + pt;
    unsigned ow = *(const unsigned*)(row + ch * 2);
    float ox = bf_lo(ow);
    float oy = bf_hi(ow);
    float s = 3.f * __builtin_amdgcn_rcpf(1.f + __expf(-bf2f(row[576 + ch])));
    float bx = (float)px + ox + fx;
    float by = (float)py + oy + fy;
    const unsigned short* vbase = vsb + l * 64 + m * 8;
    const unsigned short* lgp = row + 864 + m * 324 + l * 108 + pt * 9;
#pragma unroll
    for (int kk = 0; kk < 9; kk++) {
      float pnx = (float)(kk / 3 - 1);
      float pny = (float)(kk % 3 - 1);
      float ix = bx + pnx * s;
      float iy = by + pny * s;
      float wgt = __expf(bf2f(lgp[kk]));
      wsum += wgt;

      float fx0 = floorf(ix), fy0 = floorf(iy);
      int x0 = (int)fx0, y0 = (int)fy0;
      float wx1 = ix - fx0, wy1 = iy - fy0;
      float wx0 = 1.f - wx1, wy0 = 1.f - wy1;

      float tw[4];
      int tx[4], ty[4];
      tw[0] = wx0 * wy0; tx[0] = x0;     ty[0] = y0;
      tw[1] = wx1 * wy0; tx[1] = x0 + 1; ty[1] = y0;
      tw[2] = wx0 * wy1; tx[2] = x0;     ty[2] = y0 + 1;
      tw[3] = wx1 * wy1; tx[3] = x0 + 1; ty[3] = y0 + 1;
#pragma unroll
      for (int c = 0; c < 4; c++) {
        if ((unsigned)tx[c] < 64u && (unsigned)ty[c] < 64u) {
          uint4 uv = *(const uint4*)(vbase + (size_t)(ty[c] * 64 + tx[c]) * 192);
          float ww = wgt * tw[c];
          acc[0] += ww * bf_lo(uv.x); acc[1] += ww * bf_hi(uv.x);
          acc[2] += ww * bf_lo(uv.y); acc[3] += ww * bf_hi(uv.y);
          acc[4] += ww * bf_lo(uv.z); acc[5] += ww * bf_hi(uv.z);
          acc[6] += ww * bf_lo(uv.w); acc[7] += ww * bf_hi(uv.w);
        }
      }
    }
  }
#pragma unroll
  for (int mask = 1; mask < 16; mask <<= 1) {
    wsum += __shfl_xor(wsum, mask);
#pragma unroll
    for (int d = 0; d < 8; d++) acc[d] += __shfl_xor(acc[d], mask);
  }
  if (yl < 8) {
    float inv = __builtin_amdgcn_rcpf(wsum);
    float r = 0.f;
#pragma unroll
    for (int d = 0; d < 8; d++) r = (d == yl) ? acc[d] : r;
    featb[(size_t)p * 64 + m * 8 + yl] = f2bf(r * inv);
  }
}

// Fused output convs: out = W2·lrelu(W1·feat + b1) + b2 + x0, coalesced fp32 [co][p] store.
// Block = 64 pixels; GEMM1 -> LDS (bf16, stride 72) -> transposed GEMM2.
__global__ __launch_bounds__(256) void k_opout(const unsigned short* __restrict__ featb,
                                               const unsigned short* __restrict__ o1b,
                                               const float* __restrict__ bias1,
                                               const unsigned short* __restrict__ o2b,
                                               const float* __restrict__ bias2,
                                               const float* __restrict__ x,
                                               float* __restrict__ out) {
  __shared__ unsigned short hop[64 * 72];
  int wv = threadIdx.x >> 6;
  int l = threadIdx.x & 63;
  int lm = l & 15, lq = l >> 4;
  int bp0 = blockIdx.x * 64;

  // GEMM1: pixels bp0+wv*16.., all 64 hop channels
  f32x4 acc1[4];
#pragma unroll
  for (int nt = 0; nt < 4; nt++) {
    float bv = bias1[nt * 16 + lm];
    acc1[nt] = (f32x4){bv, bv, bv, bv};
  }
  const unsigned short* ap = featb + (size_t)(bp0 + wv * 16 + lm) * 64 + lq * 8;
#pragma unroll
  for (int k0 = 0; k0 < 64; k0 += 32) {
    short8 af = *(const short8*)(ap + k0);
#pragma unroll
    for (int nt = 0; nt < 4; nt++) {
      short8 bf = *(const short8*)(o1b + (size_t)(nt * 16 + lm) * 64 + lq * 8 + k0);
      acc1[nt] = __builtin_amdgcn_mfma_f32_16x16x32_bf16(af, bf, acc1[nt], 0, 0, 0);
    }
  }
#pragma unroll
  for (int nt = 0; nt < 4; nt++)
#pragma unroll
    for (int r = 0; r < 4; r++)
      hop[(wv * 16 + lq * 4 + r) * 72 + nt * 16 + lm] = f2bf(lrelu_f(acc1[nt][r]));
  __syncthreads();

  // GEMM2 transposed: wave's co rows wv*16.., all 64 pixels of block
  f32x4 b4;
#pragma unroll
  for (int r = 0; r < 4; r++) b4[r] = bias2[wv * 16 + lq * 4 + r];
  f32x4 acc2[4];
#pragma unroll
  for (int pg = 0; pg < 4; pg++) acc2[pg] = b4;
#pragma unroll
  for (int k0 = 0; k0 < 64; k0 += 32) {
    short8 af = *(const short8*)(o2b + (size_t)(wv * 16 + lm) * 64 + k0 + lq * 8);
#pragma unroll
    for (int pg = 0; pg < 4; pg++) {
      short8 bf = *(const short8*)(hop + (pg * 16 + lm) * 72 + k0 + lq * 8);
      acc2[pg] = __builtin_amdgcn_mfma_f32_16x16x32_bf16(af, bf, acc2[pg], 0, 0, 0);
    }
  }
#pragma unroll
  for (int pg = 0; pg < 4; pg++) {
#pragma unroll
    for (int r = 0; r < 4; r++) {
      int co = wv * 16 + lq * 4 + r;
      int p = bp0 + pg * 16 + lm;
      out[(size_t)co * HWN + p] = acc2[pg][r] + x[(size_t)co * HWN + p];
    }
  }
}

extern "C" void kernel_launch(void* const* d_in, const int* in_sizes, int n_in,
                              void* d_out, int out_size, void* d_ws, size_t ws_size,
                              hipStream_t stream) {
  const float* x     = (const float*)d_in[0];
  const float* flow1 = (const float*)d_in[1];
  const float* flow2 = (const float*)d_in[2];
  const float* aw_w1 = (const float*)d_in[5];
  const float* aw_b1 = (const float*)d_in[6];
  const float* aw_w2 = (const float*)d_in[7];
  const float* aw_b2 = (const float*)d_in[8];
  const float* aw_w3 = (const float*)d_in[9];
  const float* aw_b3 = (const float*)d_in[10];
  const float* aw_w4 = (const float*)d_in[11];
  const float* aw_b4 = (const float*)d_in[12];
  const float* so_w1 = (const float*)d_in[13];
  const float* so_b1 = (const float*)d_in[14];
  const float* so_w2 = (const float*)d_in[15];
  const float* so_b2 = (const float*)d_in[16];
  const float* so_w3 = (const float*)d_in[17];
  const float* so_b3 = (const float*)d_in[18];
  const float* so_w4 = (const float*)d_in[19];
  const float* so_b4 = (const float*)d_in[20];
  const float* po_w1 = (const float*)d_in[21];
  const float* po_b1 = (const float*)d_in[22];
  const float* po_w2 = (const float*)d_in[23];
  const float* po_b2 = (const float*)d_in[24];
  const float* po_w3 = (const float*)d_in[25];
  const float* po_b3 = (const float*)d_in[26];
  const float* po_w4 = (const float*)d_in[27];
  const float* po_b4 = (const float*)d_in[28];
  const float* vp_w  = (const float*)d_in[29];
  const float* vp_b  = (const float*)d_in[30];
  const float* op_w1 = (const float*)d_in[31];
  const float* op_b1 = (const float*)d_in[32];
  const float* op_w2 = (const float*)d_in[33];
  const float* op_b2 = (const float*)d_in[34];

  char* base = (char*)d_ws;
  size_t off = 0;
  auto alloc = [&](size_t bytes) { void* pp = base + off; off = (off + bytes + 255) & ~(size_t)255; return pp; };

  float* fcn2  = (float*)alloc(2 * HWN * 4);
  unsigned short* xb    = (unsigned short*)alloc(192 * HWN * 2);
  unsigned short* vsb   = (unsigned short*)alloc(192 * HWN * 2);
  unsigned short* extra = (unsigned short*)alloc(224 * HWN * 2);
  unsigned short* h1    = (unsigned short*)alloc(192 * HWN * 2);
  unsigned short* h2    = (unsigned short*)alloc(192 * HWN * 2);
  unsigned short* h3    = (unsigned short*)alloc(192 * HWN * 2);
  unsigned short* to    = (unsigned short*)alloc((size_t)3456 * HWN * 2);
  unsigned short* featb = (unsigned short*)alloc(64 * HWN * 2);
  unsigned short* Wtail = (unsigned short*)alloc(3456 * 64 * 2);
  float* btail = (float*)alloc(3456 * 4);
  float* b1c   = (float*)alloc(192 * 4);
  float* b2c   = (float*)alloc(192 * 4);
  float* b3c   = (float*)alloc(192 * 4);
  unsigned short* o1b = (unsigned short*)alloc(64 * 64 * 2);
  unsigned short* o2b = (unsigned short*)alloc(64 * 64 * 2);
  unsigned short* W1  = (unsigned short*)alloc(192 * 224 * 2);
  unsigned short* W2g = (unsigned short*)alloc(3 * 64 * 576 * 2);
  unsigned short* W3g = (unsigned short*)alloc(3 * 64 * 576 * 2);
  unsigned short* vpb = (unsigned short*)alloc(192 * 192 * 2);

  k_pre<<<5392, 256, 0, stream>>>(
      x, flow1, flow2,
      so_w4, po_w4, aw_w4, so_b4, po_b4, aw_b4,
      so_b1, po_b1, aw_b1, so_b2, po_b2, aw_b2, so_b3, po_b3, aw_b3,
      so_w1, po_w1, aw_w1, so_w2, po_w2, aw_w2, so_w3, po_w3, aw_w3,
      op_w1, op_w2, vp_w,
      Wtail, btail, b1c, b2c, b3c, o1b, o2b, W1, W2g, W3g, vpb, xb, fcn2);

  k_extra<<<1024, 256, 0, stream>>>(xb, flow1, fcn2, extra);

  // z=0: value proj xb->vsb; z=1: trunk head extra->h1
  k_gemm2<<<dim3(64, 3, 2), 256, 0, stream>>>(xb, vpb, vp_b, vsb, extra, W1, b1c, h1);

  k_conv3g<<<dim3(64, 2, 3), 256, 0, stream>>>(h1, W2g, b2c, h2);
  k_conv3g<<<dim3(64, 2, 3), 256, 0, stream>>>(h2, W3g, b3c, h3);
  k_tail<<<dim3(64, 108), 256, 0, stream>>>(h3, Wtail, btail, to);

  k_msdeform<<<dim3(256, 8), 256, 0, stream>>>(vsb, to, flow1, fcn2, featb);

  k_opout<<<64, 256, 0, stream>>>(featb, o1b, op_b1, o2b, op_b2, x, (float*)d_out);
}

// Round 6
// 239.236 us; speedup vs baseline: 3.4462x; 1.0122x over previous
//
#include <hip/hip_runtime.h>
#include <hip/hip_bf16.h>
#include <math.h>

// Problem constants: n=1, t=3(=L), c=64, h=w=64, M=8 heads, D=8, P=12, KK=9
#define HWN 4096

typedef __attribute__((ext_vector_type(8))) short short8;   // 8 bf16 (4 VGPRs)
typedef __attribute__((ext_vector_type(4))) float f32x4;    // MFMA C/D

__device__ __forceinline__ float lrelu_f(float v) { return v >= 0.f ? v : 0.1f * v; }

__device__ __forceinline__ unsigned short f2bf(float f) {
  union { float f; unsigned u; } v; v.f = f;
  unsigned r = v.u + 0x7fff + ((v.u >> 16) & 1);   // round-to-nearest-even
  return (unsigned short)(r >> 16);
}
__device__ __forceinline__ float bf2f(unsigned short u) {
  union { unsigned u; float f; } v; v.u = ((unsigned)u) << 16;
  return v.f;
}
__device__ __forceinline__ float bf_lo(unsigned u) {
  union { unsigned u; float f; } v; v.u = u << 16; return v.f;
}
__device__ __forceinline__ float bf_hi(unsigned u) {
  union { unsigned u; float f; } v; v.u = u & 0xffff0000u; return v.f;
}

// bilinear sample with zeros padding (fp32 source)
__device__ __forceinline__ float bilin_zero(const float* __restrict__ img, float ix, float iy) {
  float fx0 = floorf(ix), fy0 = floorf(iy);
  int x0 = (int)fx0, y0 = (int)fy0;
  float wx1 = ix - fx0, wy1 = iy - fy0;
  float wx0 = 1.f - wx1, wy0 = 1.f - wy1;
  float acc = 0.f;
  if ((unsigned)y0 < 64u) {
    if ((unsigned)x0 < 64u)       acc += wx0 * wy0 * img[y0 * 64 + x0];
    if ((unsigned)(x0 + 1) < 64u) acc += wx1 * wy0 * img[y0 * 64 + x0 + 1];
  }
  if ((unsigned)(y0 + 1) < 64u) {
    if ((unsigned)x0 < 64u)       acc += wx0 * wy1 * img[(y0 + 1) * 64 + x0];
    if ((unsigned)(x0 + 1) < 64u) acc += wx1 * wy1 * img[(y0 + 1) * 64 + x0 + 1];
  }
  return acc;
}

// k_pre: all input-chain-independent prep in one launch.
// blocks [0,5184): weight staging; [5184,5376): x transpose -> xb [p][192] bf16;
// [5376,5392): flow_cn2.
__global__ void k_pre(
    const float* __restrict__ x, const float* __restrict__ flow1, const float* __restrict__ flow2,
    const float* so_w4, const float* po_w4, const float* aw_w4,
    const float* so_b4, const float* po_b4, const float* aw_b4,
    const float* so_b1, const float* po_b1, const float* aw_b1,
    const float* so_b2, const float* po_b2, const float* aw_b2,
    const float* so_b3, const float* po_b3, const float* aw_b3,
    const float* so_w1, const float* po_w1, const float* aw_w1,
    const float* so_w2, const float* po_w2, const float* aw_w2,
    const float* so_w3, const float* po_w3, const float* aw_w3,
    const float* op_w1, const float* op_w2, const float* vp_w,
    unsigned short* Wtail, float* btail, float* b1c, float* b2c, float* b3c,
    unsigned short* o1b, unsigned short* o2b, unsigned short* W1,
    unsigned short* W2g, unsigned short* W3g, unsigned short* vpb,
    unsigned short* xb, float* fcn2) {
  __shared__ unsigned short tile[64 * 65];
  int gx = blockIdx.x;
  int tid = threadIdx.x;
  if (gx < 5184) {
    int y = gx / 864;
    int t = (gx % 864) * 256 + tid;
    if (y == 0) {  // Wtail [3456][64]
      if (t < 3456 * 64) {
        int row = t >> 6, k = t & 63;
        float v = row < 576 ? so_w4[row * 64 + k]
                : row < 864 ? po_w4[(row - 576) * 64 + k]
                            : aw_w4[(row - 864) * 64 + k];
        Wtail[t] = f2bf(v);
      }
    } else if (y == 1) {  // biases + small weights
      if (t < 3456) {
        btail[t] = t < 576 ? so_b4[t] : t < 864 ? po_b4[t - 576] : aw_b4[t - 864];
      } else if (t < 3648) {
        int i = t - 3456; b1c[i] = i < 64 ? so_b1[i] : i < 128 ? po_b1[i - 64] : aw_b1[i - 128];
      } else if (t < 3840) {
        int i = t - 3648; b2c[i] = i < 64 ? so_b2[i] : i < 128 ? po_b2[i - 64] : aw_b2[i - 128];
      } else if (t < 4032) {
        int i = t - 3840; b3c[i] = i < 64 ? so_b3[i] : i < 128 ? po_b3[i - 64] : aw_b3[i - 128];
      } else if (t < 8128) {
        o1b[t - 4032] = f2bf(op_w1[t - 4032]);
      } else if (t < 12224) {
        o2b[t - 8128] = f2bf(op_w2[t - 8128]);
      }
    } else if (y == 2) {  // W1 [192][224] zero-padded K
      if (t < 192 * 224) {
        int row = t / 224, k = t % 224;
        int tr = row >> 6, lco = row & 63;
        const float* s = tr == 0 ? so_w1 : tr == 1 ? po_w1 : aw_w1;
        W1[t] = (k < 196) ? f2bf(s[lco * 196 + k]) : (unsigned short)0;
      }
    } else if (y == 3 || y == 4) {  // W2g/W3g [3][64][576], k-order kidx*64+ci
      if (t < 3 * 64 * 576) {
        int tr = t / 36864, rem = t % 36864;
        int co = rem / 576, r2 = rem % 576;
        int kidx = r2 >> 6, ci = r2 & 63;
        const float* s;
        if (y == 3) s = tr == 0 ? so_w2 : tr == 1 ? po_w2 : aw_w2;
        else        s = tr == 0 ? so_w3 : tr == 1 ? po_w3 : aw_w3;
        (y == 3 ? W2g : W3g)[t] = f2bf(s[co * 576 + ci * 9 + kidx]);
      }
    } else {  // vpb [192][192]
      if (t < 192 * 192) vpb[t] = f2bf(vp_w[t]);
    }
  } else if (gx < 5376) {  // transpose: 64-px tile x 64-ch group
    int b = gx - 5184;
    int ptile = b & 63, cg = b >> 6;  // 64 x 3
    int px = tid & 63, ch0 = (tid >> 6) * 16;
#pragma unroll
    for (int i = 0; i < 16; i++) {
      float v = x[(size_t)(cg * 64 + ch0 + i) * HWN + ptile * 64 + px];
      tile[(ch0 + i) * 65 + px] = f2bf(v);
    }
    __syncthreads();
    int c = tid & 63, pl0 = (tid >> 6) * 16;
#pragma unroll
    for (int i = 0; i < 16; i++)
      xb[(size_t)(ptile * 64 + pl0 + i) * 192 + cg * 64 + c] = tile[c * 65 + pl0 + i];
  } else {  // flow_cn2
    int p = (gx - 5376) * 256 + tid;
    int px = p & 63, py = p >> 6;
    float fx = flow1[p], fy = flow1[HWN + p];
    float ix = (float)px + fx, iy = (float)py + fy;
    fcn2[p] = fx + bilin_zero(flow2, ix, iy);
    fcn2[HWN + p] = fy + bilin_zero(flow2 + HWN, ix, iy);
  }
}

// k_extra: wave per pixel, lane = channel. All accesses coalesced.
__global__ void k_extra(const unsigned short* __restrict__ xb, const float* __restrict__ flow1,
                        const float* __restrict__ fcn2, unsigned short* __restrict__ extra) {
  int w = threadIdx.x >> 6, c = threadIdx.x & 63;
  int p = blockIdx.x * 4 + w;
  int px = p & 63, py = p >> 6;
  float fx1 = flow1[p], fy1 = flow1[HWN + p];
  float fx2 = fcn2[p],  fy2 = fcn2[HWN + p];
  extra[(size_t)p * 224 + c] = xb[(size_t)p * 192 + c];
#pragma unroll
  for (int lev = 0; lev < 2; lev++) {
    float ix = (float)px + (lev ? fx2 : fx1);
    float iy = (float)py + (lev ? fy2 : fy1);
    float fx0 = floorf(ix), fy0 = floorf(iy);
    int x0 = (int)fx0, y0 = (int)fy0;
    float wx1 = ix - fx0, wy1 = iy - fy0;
    float wx0 = 1.f - wx1, wy0 = 1.f - wy1;
    int coff = (lev + 1) * 64;
    float acc = 0.f;
    if ((unsigned)y0 < 64u) {
      if ((unsigned)x0 < 64u)       acc += wx0 * wy0 * bf2f(xb[(size_t)(y0 * 64 + x0) * 192 + coff + c]);
      if ((unsigned)(x0 + 1) < 64u) acc += wx1 * wy0 * bf2f(xb[(size_t)(y0 * 64 + x0 + 1) * 192 + coff + c]);
    }
    if ((unsigned)(y0 + 1) < 64u) {
      if ((unsigned)x0 < 64u)       acc += wx0 * wy1 * bf2f(xb[(size_t)((y0 + 1) * 64 + x0) * 192 + coff + c]);
      if ((unsigned)(x0 + 1) < 64u) acc += wx1 * wy1 * bf2f(xb[(size_t)((y0 + 1) * 64 + x0 + 1) * 192 + coff + c]);
    }
    extra[(size_t)p * 224 + coff + c] = f2bf(acc);
  }
  if (c < 2) {
    extra[(size_t)p * 224 + 192 + c] = f2bf(flow1[c * HWN + p]);
    extra[(size_t)p * 224 + 194 + c] = f2bf(fcn2[c * HWN + p]);
  }
  if (c < 28) extra[(size_t)p * 224 + 196 + c] = 0;
}

// Two GEMMs in one dispatch (blockIdx.z): z=0 value-proj (K=192, no act),
// z=1 trunk head (K=224, lrelu). 128-thr blocks, 32px x 32co tiles -> 12 waves/CU.
__global__ __launch_bounds__(128) void k_gemm2(
    const unsigned short* __restrict__ A0, const unsigned short* __restrict__ Wm0,
    const float* __restrict__ bias0, unsigned short* __restrict__ out0,
    const unsigned short* __restrict__ A1, const unsigned short* __restrict__ Wm1,
    const float* __restrict__ bias1, unsigned short* __restrict__ out1) {
  int z = blockIdx.z;
  const unsigned short* A = z ? A1 : A0;
  const unsigned short* Wm = z ? Wm1 : Wm0;
  const float* bias = z ? bias1 : bias0;
  unsigned short* out = z ? out1 : out0;
  int K = z ? 224 : 192;

  int wv = threadIdx.x >> 6;  // 0..1
  int l = threadIdx.x & 63;
  int lm = l & 15, lq = l >> 4;
  int p0 = blockIdx.x * 32 + wv * 16;
  int co0 = blockIdx.y * 32;

  f32x4 acc[2];
#pragma unroll
  for (int nt = 0; nt < 2; nt++) {
    float bv = bias[co0 + nt * 16 + lm];
    acc[nt] = (f32x4){bv, bv, bv, bv};
  }
  const unsigned short* ap = A + (size_t)(p0 + lm) * K + lq * 8;
  const unsigned short* wp = Wm + (size_t)(co0 + lm) * K + lq * 8;
  for (int k0 = 0; k0 < K; k0 += 32) {
    short8 af = *(const short8*)(ap + k0);
#pragma unroll
    for (int nt = 0; nt < 2; nt++) {
      short8 bf = *(const short8*)(wp + (size_t)nt * 16 * K + k0);
      acc[nt] = __builtin_amdgcn_mfma_f32_16x16x32_bf16(af, bf, acc[nt], 0, 0, 0);
    }
  }
#pragma unroll
  for (int nt = 0; nt < 2; nt++) {
    int co = co0 + nt * 16 + lm;
#pragma unroll
    for (int r = 0; r < 4; r++) {
      int p = p0 + lq * 4 + r;
      float v = acc[nt][r];
      if (z) v = lrelu_f(v);
      out[(size_t)p * 192 + co] = f2bf(v);
    }
  }
}

// Grouped direct 3x3 conv (pad 1) as MFMA GEMM over shifted rows of h [p][192].
// 128-thr blocks, 32px x 16co tiles -> grid (128,4,3) = 12 waves/CU.
__global__ __launch_bounds__(128) void k_conv3g(const unsigned short* __restrict__ h,
                                                const unsigned short* __restrict__ Wm,
                                                const float* __restrict__ bias,
                                                unsigned short* __restrict__ out) {
  int wv = threadIdx.x >> 6;
  int l = threadIdx.x & 63;
  int lm = l & 15, lq = l >> 4;
  int p0 = blockIdx.x * 32 + wv * 16;
  int co0 = blockIdx.y * 16;
  int t = blockIdx.z;
  int p = p0 + lm;
  int px = p & 63, py = p >> 6;

  float bv = bias[t * 64 + co0 + lm];
  f32x4 acc = (f32x4){bv, bv, bv, bv};
  const unsigned short* wp = Wm + ((size_t)t * 64 + co0 + lm) * 576 + lq * 8;
#pragma unroll
  for (int kidx = 0; kidx < 9; kidx++) {
    int ky = kidx / 3, kx = kidx % 3;
    int pp = p + (ky - 1) * 64 + (kx - 1);
    bool valid = ((unsigned)(px + kx - 1) < 64u) && ((unsigned)(py + ky - 1) < 64u);
    const unsigned short* apb = h + (size_t)pp * 192 + t * 64 + lq * 8;
#pragma unroll
    for (int c2 = 0; c2 < 2; c2++) {
      short8 af = {};
      if (valid) af = *(const short8*)(apb + c2 * 32);
      short8 bf = *(const short8*)(wp + kidx * 64 + c2 * 32);
      acc = __builtin_amdgcn_mfma_f32_16x16x32_bf16(af, bf, acc, 0, 0, 0);
    }
  }
#pragma unroll
  for (int r = 0; r < 4; r++) {
    int po_ = p0 + lq * 4 + r;
    out[(size_t)po_ * 192 + t * 64 + co0 + lm] = f2bf(lrelu_f(acc[r]));
  }
}

// Fused tail GEMM: all three trunk 1x1 tails. A = h3 [p][192] (col offset t*64),
// W = Wtail [3456][64], out bf16 [p][3456]. Epilogue bakes in the msdeform
// per-element transforms: exp() for aw logits, 3*sigmoid for po scales.
__global__ __launch_bounds__(256) void k_tail(const unsigned short* __restrict__ A,
                                              const unsigned short* __restrict__ Wm,
                                              const float* __restrict__ bias,
                                              unsigned short* __restrict__ out) {
  int wv = threadIdx.x >> 6;
  int l = threadIdx.x & 63;
  int lm = l & 15, lq = l >> 4;
  int p0 = blockIdx.x * 64 + wv * 16;
  int co0 = blockIdx.y * 32;
  int t = (co0 < 576) ? 0 : (co0 < 864 ? 1 : 2);

  f32x4 acc[2];
#pragma unroll
  for (int nt = 0; nt < 2; nt++) {
    float bv = bias[co0 + nt * 16 + lm];
    acc[nt] = (f32x4){bv, bv, bv, bv};
  }
  const unsigned short* ap = A + (size_t)(p0 + lm) * 192 + t * 64 + lq * 8;
  const unsigned short* wp = Wm + (size_t)(co0 + lm) * 64 + lq * 8;
#pragma unroll
  for (int k0 = 0; k0 < 64; k0 += 32) {
    short8 af = *(const short8*)(ap + k0);
#pragma unroll
    for (int nt = 0; nt < 2; nt++) {
      short8 bf = *(const short8*)(wp + (size_t)nt * 16 * 64 + k0);
      acc[nt] = __builtin_amdgcn_mfma_f32_16x16x32_bf16(af, bf, acc[nt], 0, 0, 0);
    }
  }
#pragma unroll
  for (int nt = 0; nt < 2; nt++) {
    int co = co0 + nt * 16 + lm;
#pragma unroll
    for (int r = 0; r < 4; r++) {
      int p = p0 + lq * 4 + r;
      float v = acc[nt][r];
      if (t == 2) v = __expf(v);                                            // aw -> exp(logit)
      else if (t == 1) v = 3.f * __builtin_amdgcn_rcpf(1.f + __expf(-v));   // po -> 3*sigmoid
      out[(size_t)p * 3456 + co] = f2bf(v);
    }
  }
}

// Fused softmax + deformable sampling; 16 lanes cooperate per (pixel, head).
// to [p][3456]: cols 0..575 off, 576..863 s=3*sigmoid(po), 864..3455 exp(aw logits).
// vsb bf16 [p][192].
__global__ void k_msdeform(const unsigned short* __restrict__ vsb,
                           const unsigned short* __restrict__ to,
                           const float* __restrict__ flow1, const float* __restrict__ fcn2,
                           unsigned short* __restrict__ featb) {
  int yl = threadIdx.x & 15;
  int p = blockIdx.x * 16 + (threadIdx.x >> 4);
  int m = blockIdx.y;
  int px = p & 63, py = p >> 6;

  float fx1 = flow1[p], fy1 = flow1[HWN + p];
  float fx2 = fcn2[p],  fy2 = fcn2[HWN + p];

  const unsigned short* row = to + (size_t)p * 3456;

  float acc[8];
#pragma unroll
  for (int d = 0; d < 8; d++) acc[d] = 0.f;
  float wsum = 0.f;

  for (int pair = yl; pair < 36; pair += 16) {
    int l = pair / 12, pt = pair % 12;
    float fx = (l == 1) ? fx1 : ((l == 2) ? fx2 : 0.f);
    float fy = (l == 1) ? fy1 : ((l == 2) ? fy2 : 0.f);
    int ch = (m * 3 + l) * 12 + pt;
    unsigned ow = *(const unsigned*)(row + ch * 2);
    float ox = bf_lo(ow);
    float oy = bf_hi(ow);
    float s = bf2f(row[576 + ch]);         // pre-transformed: 3*sigmoid(po)
    float bx = (float)px + ox + fx;
    float by = (float)py + oy + fy;
    const unsigned short* vbase = vsb + l * 64 + m * 8;
    const unsigned short* lgp = row + 864 + m * 324 + l * 108 + pt * 9;
#pragma unroll
    for (int kk = 0; kk < 9; kk++) {
      float pnx = (float)(kk / 3 - 1);
      float pny = (float)(kk % 3 - 1);
      float ix = bx + pnx * s;
      float iy = by + pny * s;
      float wgt = bf2f(lgp[kk]);           // pre-transformed: exp(logit)
      wsum += wgt;

      float fx0 = floorf(ix), fy0 = floorf(iy);
      int x0 = (int)fx0, y0 = (int)fy0;
      float wx1 = ix - fx0, wy1 = iy - fy0;
      float wx0 = 1.f - wx1, wy0 = 1.f - wy1;

      float tw[4];
      int tx[4], ty[4];
      tw[0] = wx0 * wy0; tx[0] = x0;     ty[0] = y0;
      tw[1] = wx1 * wy0; tx[1] = x0 + 1; ty[1] = y0;
      tw[2] = wx0 * wy1; tx[2] = x0;     ty[2] = y0 + 1;
      tw[3] = wx1 * wy1; tx[3] = x0 + 1; ty[3] = y0 + 1;
#pragma unroll
      for (int c = 0; c < 4; c++) {
        if ((unsigned)tx[c] < 64u && (unsigned)ty[c] < 64u) {
          uint4 uv = *(const uint4*)(vbase + (size_t)(ty[c] * 64 + tx[c]) * 192);
          float ww = wgt * tw[c];
          acc[0] += ww * bf_lo(uv.x); acc[1] += ww * bf_hi(uv.x);
          acc[2] += ww * bf_lo(uv.y); acc[3] += ww * bf_hi(uv.y);
          acc[4] += ww * bf_lo(uv.z); acc[5] += ww * bf_hi(uv.z);
          acc[6] += ww * bf_lo(uv.w); acc[7] += ww * bf_hi(uv.w);
        }
      }
    }
  }
#pragma unroll
  for (int mask = 1; mask < 16; mask <<= 1) {
    wsum += __shfl_xor(wsum, mask);
#pragma unroll
    for (int d = 0; d < 8; d++) acc[d] += __shfl_xor(acc[d], mask);
  }
  if (yl < 8) {
    float inv = __builtin_amdgcn_rcpf(wsum);
    float r = 0.f;
#pragma unroll
    for (int d = 0; d < 8; d++) r = (d == yl) ? acc[d] : r;
    featb[(size_t)p * 64 + m * 8 + yl] = f2bf(r * inv);
  }
}

// Fused output convs: out = W2·lrelu(W1·feat + b1) + b2 + x0, coalesced fp32 [co][p] store.
// Block = 64 pixels; GEMM1 -> LDS (bf16, stride 72) -> transposed GEMM2.
__global__ __launch_bounds__(256) void k_opout(const unsigned short* __restrict__ featb,
                                               const unsigned short* __restrict__ o1b,
                                               const float* __restrict__ bias1,
                                               const unsigned short* __restrict__ o2b,
                                               const float* __restrict__ bias2,
                                               const float* __restrict__ x,
                                               float* __restrict__ out) {
  __shared__ unsigned short hop[64 * 72];
  int wv = threadIdx.x >> 6;
  int l = threadIdx.x & 63;
  int lm = l & 15, lq = l >> 4;
  int bp0 = blockIdx.x * 64;

  f32x4 acc1[4];
#pragma unroll
  for (int nt = 0; nt < 4; nt++) {
    float bv = bias1[nt * 16 + lm];
    acc1[nt] = (f32x4){bv, bv, bv, bv};
  }
  const unsigned short* ap = featb + (size_t)(bp0 + wv * 16 + lm) * 64 + lq * 8;
#pragma unroll
  for (int k0 = 0; k0 < 64; k0 += 32) {
    short8 af = *(const short8*)(ap + k0);
#pragma unroll
    for (int nt = 0; nt < 4; nt++) {
      short8 bf = *(const short8*)(o1b + (size_t)(nt * 16 + lm) * 64 + lq * 8 + k0);
      acc1[nt] = __builtin_amdgcn_mfma_f32_16x16x32_bf16(af, bf, acc1[nt], 0, 0, 0);
    }
  }
#pragma unroll
  for (int nt = 0; nt < 4; nt++)
#pragma unroll
    for (int r = 0; r < 4; r++)
      hop[(wv * 16 + lq * 4 + r) * 72 + nt * 16 + lm] = f2bf(lrelu_f(acc1[nt][r]));
  __syncthreads();

  f32x4 b4;
#pragma unroll
  for (int r = 0; r < 4; r++) b4[r] = bias2[wv * 16 + lq * 4 + r];
  f32x4 acc2[4];
#pragma unroll
  for (int pg = 0; pg < 4; pg++) acc2[pg] = b4;
#pragma unroll
  for (int k0 = 0; k0 < 64; k0 += 32) {
    short8 af = *(const short8*)(o2b + (size_t)(wv * 16 + lm) * 64 + k0 + lq * 8);
#pragma unroll
    for (int pg = 0; pg < 4; pg++) {
      short8 bf = *(const short8*)(hop + (pg * 16 + lm) * 72 + k0 + lq * 8);
      acc2[pg] = __builtin_amdgcn_mfma_f32_16x16x32_bf16(af, bf, acc2[pg], 0, 0, 0);
    }
  }
#pragma unroll
  for (int pg = 0; pg < 4; pg++) {
#pragma unroll
    for (int r = 0; r < 4; r++) {
      int co = wv * 16 + lq * 4 + r;
      int p = bp0 + pg * 16 + lm;
      out[(size_t)co * HWN + p] = acc2[pg][r] + x[(size_t)co * HWN + p];
    }
  }
}

extern "C" void kernel_launch(void* const* d_in, const int* in_sizes, int n_in,
                              void* d_out, int out_size, void* d_ws, size_t ws_size,
                              hipStream_t stream) {
  const float* x     = (const float*)d_in[0];
  const float* flow1 = (const float*)d_in[1];
  const float* flow2 = (const float*)d_in[2];
  const float* aw_w1 = (const float*)d_in[5];
  const float* aw_b1 = (const float*)d_in[6];
  const float* aw_w2 = (const float*)d_in[7];
  const float* aw_b2 = (const float*)d_in[8];
  const float* aw_w3 = (const float*)d_in[9];
  const float* aw_b3 = (const float*)d_in[10];
  const float* aw_w4 = (const float*)d_in[11];
  const float* aw_b4 = (const float*)d_in[12];
  const float* so_w1 = (const float*)d_in[13];
  const float* so_b1 = (const float*)d_in[14];
  const float* so_w2 = (const float*)d_in[15];
  const float* so_b2 = (const float*)d_in[16];
  const float* so_w3 = (const float*)d_in[17];
  const float* so_b3 = (const float*)d_in[18];
  const float* so_w4 = (const float*)d_in[19];
  const float* so_b4 = (const float*)d_in[20];
  const float* po_w1 = (const float*)d_in[21];
  const float* po_b1 = (const float*)d_in[22];
  const float* po_w2 = (const float*)d_in[23];
  const float* po_b2 = (const float*)d_in[24];
  const float* po_w3 = (const float*)d_in[25];
  const float* po_b3 = (const float*)d_in[26];
  const float* po_w4 = (const float*)d_in[27];
  const float* po_b4 = (const float*)d_in[28];
  const float* vp_w  = (const float*)d_in[29];
  const float* vp_b  = (const float*)d_in[30];
  const float* op_w1 = (const float*)d_in[31];
  const float* op_b1 = (const float*)d_in[32];
  const float* op_w2 = (const float*)d_in[33];
  const float* op_b2 = (const float*)d_in[34];

  char* base = (char*)d_ws;
  size_t off = 0;
  auto alloc = [&](size_t bytes) { void* pp = base + off; off = (off + bytes + 255) & ~(size_t)255; return pp; };

  float* fcn2  = (float*)alloc(2 * HWN * 4);
  unsigned short* xb    = (unsigned short*)alloc(192 * HWN * 2);
  unsigned short* vsb   = (unsigned short*)alloc(192 * HWN * 2);
  unsigned short* extra = (unsigned short*)alloc(224 * HWN * 2);
  unsigned short* h1    = (unsigned short*)alloc(192 * HWN * 2);
  unsigned short* h2    = (unsigned short*)alloc(192 * HWN * 2);
  unsigned short* h3    = (unsigned short*)alloc(192 * HWN * 2);
  unsigned short* to    = (unsigned short*)alloc((size_t)3456 * HWN * 2);
  unsigned short* featb = (unsigned short*)alloc(64 * HWN * 2);
  unsigned short* Wtail = (unsigned short*)alloc(3456 * 64 * 2);
  float* btail = (float*)alloc(3456 * 4);
  float* b1c   = (float*)alloc(192 * 4);
  float* b2c   = (float*)alloc(192 * 4);
  float* b3c   = (float*)alloc(192 * 4);
  unsigned short* o1b = (unsigned short*)alloc(64 * 64 * 2);
  unsigned short* o2b = (unsigned short*)alloc(64 * 64 * 2);
  unsigned short* W1  = (unsigned short*)alloc(192 * 224 * 2);
  unsigned short* W2g = (unsigned short*)alloc(3 * 64 * 576 * 2);
  unsigned short* W3g = (unsigned short*)alloc(3 * 64 * 576 * 2);
  unsigned short* vpb = (unsigned short*)alloc(192 * 192 * 2);

  k_pre<<<5392, 256, 0, stream>>>(
      x, flow1, flow2,
      so_w4, po_w4, aw_w4, so_b4, po_b4, aw_b4,
      so_b1, po_b1, aw_b1, so_b2, po_b2, aw_b2, so_b3, po_b3, aw_b3,
      so_w1, po_w1, aw_w1, so_w2, po_w2, aw_w2, so_w3, po_w3, aw_w3,
      op_w1, op_w2, vp_w,
      Wtail, btail, b1c, b2c, b3c, o1b, o2b, W1, W2g, W3g, vpb, xb, fcn2);

  k_extra<<<1024, 256, 0, stream>>>(xb, flow1, fcn2, extra);

  // z=0: value proj xb->vsb; z=1: trunk head extra->h1  (12 waves/CU)
  k_gemm2<<<dim3(128, 6, 2), 128, 0, stream>>>(xb, vpb, vp_b, vsb, extra, W1, b1c, h1);

  k_conv3g<<<dim3(128, 4, 3), 128, 0, stream>>>(h1, W2g, b2c, h2);
  k_conv3g<<<dim3(128, 4, 3), 128, 0, stream>>>(h2, W3g, b3c, h3);
  k_tail<<<dim3(64, 108), 256, 0, stream>>>(h3, Wtail, btail, to);

  k_msdeform<<<dim3(256, 8), 256, 0, stream>>>(vsb, to, flow1, fcn2, featb);

  k_opout<<<64, 256, 0, stream>>>(featb, o1b, op_b1, o2b, op_b2, x, (float*)d_out);
}